// Round 6
// baseline (599.113 us; speedup 1.0000x reference)
//
#include <hip/hip_runtime.h>
#include <hip/hip_bf16.h>

// ---------------------------------------------------------------------------
// MLDecoder classification head, MI355X bf16-MFMA implementation.
// B=64, C_IN=2048, H=W=14 (S=196), D=768, FF=2048, G=100, NC=9605, NH=8, HD=96
// ---------------------------------------------------------------------------

#define B_    64
#define CIN_  2048
#define S_    196
#define D_    768
#define FF_   2048
#define G_    100
#define NC_   9605
#define NH_   8
#define HD_   96
#define DF_   97
#define FP_   112          // DF_ padded to 16
#define GP_   112          // G padded to 16
#define SP_   224          // S padded to 32 (7 K-steps) for P / V^T
#define BS_   (B_ * S_)   // 12544
#define BG_   (B_ * G_)   // 6400

typedef __bf16 bf16x8 __attribute__((ext_vector_type(8)));
typedef float  f32x4  __attribute__((ext_vector_type(4)));
typedef ushort us8    __attribute__((ext_vector_type(8)));

__device__ __forceinline__ float bf2f(ushort u) {
  union { unsigned int i; float f; } v; v.i = ((unsigned int)u) << 16; return v.f;
}
__device__ __forceinline__ ushort f2bf(float f) {
  __hip_bfloat16 h = __float2bfloat16(f);
  return *reinterpret_cast<ushort*>(&h);
}

// async global->LDS, 16 bytes per lane. LDS target must be wave-uniform base
// + lane*16 (our staging layouts satisfy this: lds byte offset == 16*i, i linear in t).
__device__ __forceinline__ void gl2lds16(const ushort* g, ushort* l) {
  __builtin_amdgcn_global_load_lds((const __attribute__((address_space(1))) unsigned int*)g,
                                   (__attribute__((address_space(3))) unsigned int*)l, 16, 0, 0);
}

// ---------------------------------------------------------------------------
// k_prep (R13): TINY — only wemb/wq converts + tgt LN. The x-transpose is
// GONE: the embed GEMM now reads x directly with a transposing reg-staged
// A-path (eliminates 51 MB aemb write + ~40 MB re-read + a ~56 us dispatch).
// ---------------------------------------------------------------------------
#define CVP_BLKS 1024   // cvt: wemb + wq, grid-stride, 8-float units
#define TG_BLKS  128    // tgt LN rows (padded)

struct PrepArgs {
  const float* csrc[2]; ushort* cdst[2]; int cn4[2]; int ctotal;  // 8-float units
  const float* qe; const float* g1; const float* be1;
  float* tgt; ushort* tgtB;
};

__global__ __launch_bounds__(256) void k_prep(PrepArgs pa) {
  __shared__ float r1[256], r2[256];
  int jid = blockIdx.x;
  const int t = threadIdx.x;

  if (jid < CVP_BLKS) {
    // wemb + wq fp32 -> bf16, 8 floats per unit.
    int i = jid * 256 + t;
    const int stride = CVP_BLKS * 256;
    for (; i < pa.ctotal; i += stride) {
      int seg = 0, off = i;
      while (off >= pa.cn4[seg]) { off -= pa.cn4[seg]; ++seg; }
      const float4* sp = (const float4*)pa.csrc[seg];
      float4 v0 = sp[2 * off], v1 = sp[2 * off + 1];
      us8 o;
      o[0] = f2bf(v0.x); o[1] = f2bf(v0.y); o[2] = f2bf(v0.z); o[3] = f2bf(v0.w);
      o[4] = f2bf(v1.x); o[5] = f2bf(v1.y); o[6] = f2bf(v1.z); o[7] = f2bf(v1.w);
      ((us8*)pa.cdst[seg])[off] = o;
    }
    return;
  }
  jid -= CVP_BLKS;

  // tgt = LN(2*query_embed)*g1 + be1 -> fp32 [100,768] + bf16 [128,768] (pad 0)
  const int g = jid;
  if (g >= G_) {
    for (int d = t; d < D_; d += 256) pa.tgtB[(size_t)g * D_ + d] = 0;
    return;
  }
  float y[3]; float s = 0.f, sq = 0.f;
  const float* row = pa.qe + (size_t)g * D_;
  #pragma unroll
  for (int i = 0; i < 3; ++i) { float v = 2.f * row[t + i * 256]; y[i] = v; s += v; sq += v * v; }
  r1[t] = s; r2[t] = sq; __syncthreads();
  for (int o = 128; o > 0; o >>= 1) { if (t < o) { r1[t] += r1[t + o]; r2[t] += r2[t + o]; } __syncthreads(); }
  const float mean = r1[0] * (1.f / D_);
  const float var  = r2[0] * (1.f / D_) - mean * mean;
  const float w = rsqrtf(var + 1e-5f);
  #pragma unroll
  for (int i = 0; i < 3; ++i) {
    int d = t + i * 256;
    float v = (y[i] - mean) * w * pa.g1[d] + pa.be1[d];
    pa.tgt[(size_t)g * D_ + d] = v;
    pa.tgtB[(size_t)g * D_ + d] = f2bf(v);
  }
}

// ---------------- bf16 MFMA GEMM core: C[M,N] = A[M,K]*B[N,K]^T + bias -----
// 128x128 tile, BK=32, counted-vmcnt two-barrier k-loop (R11).
// KV mode (Vt != null): cols >= 768 are the V projection, written TRANSPOSED
// into VbT [bh][hd][s].
__device__ __forceinline__ void gemm_core(const ushort* __restrict__ A, const ushort* __restrict__ B,
    const float* __restrict__ bias, const float* __restrict__ bias2,
    float* __restrict__ Cf, ushort* __restrict__ Cb, ushort* __restrict__ Vt,
    int N, int K, int m0, int n0, int relu, ushort* As, ushort* Bs) {
  const int t = threadIdx.x;
  const int lane = t & 63, wave = t >> 6;
  const int quad = lane >> 4, lrow = lane & 15;
  const int wr = (wave >> 1) * 64, wc = (wave & 1) * 64;
  const int srow = t >> 2, scol = (t & 3) * 8;
  const ushort* ag = A + (size_t)(m0 + srow) * K + scol;
  const ushort* bg = B + (size_t)(n0 + srow) * K + scol;
  ushort* asw = As + t * 8;   // linear dest: byte 16*t within buffer
  ushort* bsw = Bs + t * 8;
  f32x4 acc[4][4] = {};
  gl2lds16(ag,                  asw);
  gl2lds16(ag + (size_t)64 * K, asw + 64 * 32);
  gl2lds16(bg,                  bsw);
  gl2lds16(bg + (size_t)64 * K, bsw + 64 * 32);
  int cur = 0;
  for (int k0 = 0; k0 < K; k0 += 32) {
    if (k0 + 32 < K) {                      // prefetch next k-step into other buf
      const int nb = (cur ^ 1) * (128 * 32);
      gl2lds16(ag + k0 + 32,                  asw + nb);
      gl2lds16(ag + k0 + 32 + (size_t)64 * K, asw + nb + 64 * 32);
      gl2lds16(bg + k0 + 32,                  bsw + nb);
      gl2lds16(bg + k0 + 32 + (size_t)64 * K, bsw + nb + 64 * 32);
      asm volatile("s_waitcnt vmcnt(4)" ::: "memory");   // cur staged; prefetch flying
    } else {
      asm volatile("s_waitcnt vmcnt(0)" ::: "memory");
    }
    __builtin_amdgcn_s_barrier();
    __builtin_amdgcn_sched_barrier(0);
    const ushort* as = As + cur * (128 * 32);
    const ushort* bs = Bs + cur * (128 * 32);
    bf16x8 af[4], bfr[4];
    #pragma unroll
    for (int i = 0; i < 4; ++i) af[i] = *(const bf16x8*)&as[(wr + i * 16 + lrow) * 32 + quad * 8];
    #pragma unroll
    for (int j = 0; j < 4; ++j) bfr[j] = *(const bf16x8*)&bs[(wc + j * 16 + lrow) * 32 + quad * 8];
    __builtin_amdgcn_s_setprio(1);
    #pragma unroll
    for (int i = 0; i < 4; ++i)
      #pragma unroll
      for (int j = 0; j < 4; ++j)
        acc[i][j] = __builtin_amdgcn_mfma_f32_16x16x32_bf16(af[i], bfr[j], acc[i][j], 0, 0, 0);
    __builtin_amdgcn_s_setprio(0);
    __builtin_amdgcn_sched_barrier(0);
    __builtin_amdgcn_s_barrier();           // all done reading cur -> safe to overwrite
    __builtin_amdgcn_sched_barrier(0);
    cur ^= 1;
  }
  #pragma unroll
  for (int i = 0; i < 4; ++i) {
    #pragma unroll
    for (int j = 0; j < 4; ++j) {
      const int gcol = n0 + wc + j * 16 + lrow;
      const float bv = (bias2 && gcol >= D_) ? bias2[gcol - D_] : (bias ? bias[gcol] : 0.f);
      if (Vt && gcol >= D_) {
        const int dv = gcol - D_, hh = dv / HD_, hd = dv % HD_;
        const int row0 = m0 + wr + i * 16 + quad * 4;
        const int bb = row0 / S_, ss = row0 % S_;
        ushort4 o;
        o.x = f2bf(acc[i][j][0] + bv);
        o.y = f2bf(acc[i][j][1] + bv);
        o.z = f2bf(acc[i][j][2] + bv);
        o.w = f2bf(acc[i][j][3] + bv);
        *(ushort4*)&Vt[((size_t)(bb * NH_ + hh) * HD_ + hd) * SP_ + ss] = o;
      } else {
        #pragma unroll
        for (int r = 0; r < 4; ++r) {
          const int grow = m0 + wr + i * 16 + quad * 4 + r;
          float v = acc[i][j][r] + bv;
          if (relu) v = fmaxf(v, 0.f);
          if (Cf) Cf[(size_t)grow * N + gcol] = v;
          else    Cb[(size_t)grow * N + gcol] = f2bf(v);
        }
      }
    }
  }
}

__global__ __launch_bounds__(256) void k_gemm(const ushort* __restrict__ A, const ushort* __restrict__ B,
    const float* __restrict__ bias, const float* __restrict__ bias2,
    float* __restrict__ Cf, ushort* __restrict__ Cb, ushort* __restrict__ Vt,
    int N, int K, int nbx, int nm, int relu) {
  __shared__ ushort As[2 * 128 * 32];
  __shared__ ushort Bs[2 * 128 * 32];
  const int l = blockIdx.x;
  const int mb = (l >> 3) / nbx * 8 + (l & 7);
  const int nb = (l >> 3) % nbx;
  if (mb >= nm) return;
  gemm_core(A, B, bias, bias2, Cf, Cb, Vt, N, K, mb * 128, nb * 128, relu, As, Bs);
}
static inline int swz_grid(int nm, int nbx) { return ((nm + 7) & ~7) * nbx; }

// ---------------- 64x128-tile GEMM core (R9/R11) ---------------------------
__device__ __forceinline__ void gemm_core64(const ushort* __restrict__ A, const ushort* __restrict__ B,
    const float* __restrict__ bias, ushort* __restrict__ Cb,
    int N, int K, int m0, int n0, int relu, ushort* As, ushort* Bs) {
  const int t = threadIdx.x;
  const int lane = t & 63, wave = t >> 6;
  const int quad = lane >> 4, lrow = lane & 15;
  const int wr = (wave >> 1) * 32, wc = (wave & 1) * 64;
  const int srow = t >> 2, scol = (t & 3) * 8;
  const ushort* ag = A + (size_t)(m0 + srow) * K + scol;
  const ushort* bg = B + (size_t)(n0 + srow) * K + scol;
  ushort* asw = As + t * 8;
  ushort* bsw = Bs + t * 8;
  f32x4 acc[2][4] = {};
  gl2lds16(ag,                  asw);
  gl2lds16(bg,                  bsw);
  gl2lds16(bg + (size_t)64 * K, bsw + 64 * 32);
  int cur = 0;
  for (int k0 = 0; k0 < K; k0 += 32) {
    if (k0 + 32 < K) {
      gl2lds16(ag + k0 + 32,                  asw + (cur ^ 1) * (64 * 32));
      gl2lds16(bg + k0 + 32,                  bsw + (cur ^ 1) * (128 * 32));
      gl2lds16(bg + k0 + 32 + (size_t)64 * K, bsw + (cur ^ 1) * (128 * 32) + 64 * 32);
      asm volatile("s_waitcnt vmcnt(3)" ::: "memory");
    } else {
      asm volatile("s_waitcnt vmcnt(0)" ::: "memory");
    }
    __builtin_amdgcn_s_barrier();
    __builtin_amdgcn_sched_barrier(0);
    const ushort* as = As + cur * (64 * 32);
    const ushort* bs = Bs + cur * (128 * 32);
    bf16x8 af[2], bfr[4];
    #pragma unroll
    for (int i = 0; i < 2; ++i) af[i] = *(const bf16x8*)&as[(wr + i * 16 + lrow) * 32 + quad * 8];
    #pragma unroll
    for (int j = 0; j < 4; ++j) bfr[j] = *(const bf16x8*)&bs[(wc + j * 16 + lrow) * 32 + quad * 8];
    __builtin_amdgcn_s_setprio(1);
    #pragma unroll
    for (int i = 0; i < 2; ++i)
      #pragma unroll
      for (int j = 0; j < 4; ++j)
        acc[i][j] = __builtin_amdgcn_mfma_f32_16x16x32_bf16(af[i], bfr[j], acc[i][j], 0, 0, 0);
    __builtin_amdgcn_s_setprio(0);
    __builtin_amdgcn_sched_barrier(0);
    __builtin_amdgcn_s_barrier();
    __builtin_amdgcn_sched_barrier(0);
    cur ^= 1;
  }
  #pragma unroll
  for (int i = 0; i < 2; ++i) {
    #pragma unroll
    for (int j = 0; j < 4; ++j) {
      const int gcol = n0 + wc + j * 16 + lrow;
      const float bv = bias ? bias[gcol] : 0.f;
      #pragma unroll
      for (int r = 0; r < 4; ++r) {
        const int grow = m0 + wr + i * 16 + quad * 4 + r;
        float v = acc[i][j][r] + bv;
        if (relu) v = fmaxf(v, 0.f);
        Cb[(size_t)grow * N + gcol] = f2bf(v);
      }
    }
  }
}

__global__ __launch_bounds__(256) void k_gemm64(const ushort* __restrict__ A, const ushort* __restrict__ B,
    const float* __restrict__ bias, ushort* __restrict__ Cb,
    int N, int K, int nbx, int nm, int relu) {
  __shared__ ushort As[2 * 64 * 32];
  __shared__ ushort Bs[2 * 128 * 32];
  const int l = blockIdx.x;
  const int mb = (l >> 3) / nbx * 8 + (l & 7);
  const int nb = (l >> 3) % nbx;
  if (mb >= nm) return;
  gemm_core64(A, B, bias, Cb, N, K, mb * 64, nb * 128, relu, As, Bs);
}

// ---------------- 64x128 embed core, A read DIRECTLY from x (R13) ----------
// A[row][c] = x[b][c][s], row=(b,s) flattened. Waves 0-1: reg-staged
// transpose (float4 along s -> in-reg 4x4 -> ds_write bf16); waves 2-3:
// B via gl2lds. 196%4==0 so no 4-row group crosses a batch; s%4==0 keeps
// float4 alignment. M=12544=196*64 -> 64-row tiles exact.
__device__ __forceinline__ void gemm_core64_xa(const float* __restrict__ X,
    const ushort* __restrict__ Bw, const float* __restrict__ bias, ushort* __restrict__ Cb,
    int m0, int n0, ushort* As, ushort* Bs) {
  const int t = threadIdx.x;
  const int lane = t & 63, wave = t >> 6;
  const int quad = lane >> 4, lrow = lane & 15;
  const int wr = (wave >> 1) * 32, wc = (wave & 1) * 64;
  f32x4 acc[2][4] = {};
  // A role (t<128): unit = (j = t&15: s-quad, q = t>>4: c-quad). 16 lanes of a
  // wave cover 64 contiguous s-floats (256 B) per c -> full-line coalescing.
  const int j = t & 15, q = t >> 4;
  const int arow = m0 + 4 * j;
  const float* px = X + ((size_t)(arow / S_) * CIN_) * S_ + (arow % S_);
  // B role (t>=128): 4 x gl2lds16 per k-step; dest byte 16*(t-128): linear.
  const int tb = t - 128;
  const ushort* bg = Bw + (size_t)(n0 + (tb >> 2)) * CIN_ + (tb & 3) * 8;
  ushort* bsw = Bs + tb * 8;
  for (int k0 = 0; k0 < CIN_; k0 += 32) {
    if (t < 128) {
      const float* pc = px + (size_t)(k0 + 4 * q) * S_;
      float4 a0 = *(const float4*)(pc);
      float4 a1 = *(const float4*)(pc + S_);
      float4 a2 = *(const float4*)(pc + 2 * S_);
      float4 a3 = *(const float4*)(pc + 3 * S_);
      ushort4 o0 = { f2bf(a0.x), f2bf(a1.x), f2bf(a2.x), f2bf(a3.x) };
      ushort4 o1 = { f2bf(a0.y), f2bf(a1.y), f2bf(a2.y), f2bf(a3.y) };
      ushort4 o2 = { f2bf(a0.z), f2bf(a1.z), f2bf(a2.z), f2bf(a3.z) };
      ushort4 o3 = { f2bf(a0.w), f2bf(a1.w), f2bf(a2.w), f2bf(a3.w) };
      *(ushort4*)&As[(4 * j + 0) * 32 + 4 * q] = o0;
      *(ushort4*)&As[(4 * j + 1) * 32 + 4 * q] = o1;
      *(ushort4*)&As[(4 * j + 2) * 32 + 4 * q] = o2;
      *(ushort4*)&As[(4 * j + 3) * 32 + 4 * q] = o3;
    } else {
      gl2lds16(bg + k0,                       bsw);
      gl2lds16(bg + k0 + (size_t)32 * CIN_,   bsw + 32 * 32);
      gl2lds16(bg + k0 + (size_t)64 * CIN_,   bsw + 64 * 32);
      gl2lds16(bg + k0 + (size_t)96 * CIN_,   bsw + 96 * 32);
    }
    __syncthreads();
    bf16x8 af[2], bfr[4];
    #pragma unroll
    for (int i = 0; i < 2; ++i) af[i] = *(const bf16x8*)&As[(wr + i * 16 + lrow) * 32 + quad * 8];
    #pragma unroll
    for (int jj = 0; jj < 4; ++jj) bfr[jj] = *(const bf16x8*)&Bs[(wc + jj * 16 + lrow) * 32 + quad * 8];
    __builtin_amdgcn_s_setprio(1);
    #pragma unroll
    for (int i = 0; i < 2; ++i)
      #pragma unroll
      for (int jj = 0; jj < 4; ++jj)
        acc[i][jj] = __builtin_amdgcn_mfma_f32_16x16x32_bf16(af[i], bfr[jj], acc[i][jj], 0, 0, 0);
    __builtin_amdgcn_s_setprio(0);
    __syncthreads();
  }
  #pragma unroll
  for (int i = 0; i < 2; ++i) {
    #pragma unroll
    for (int jj = 0; jj < 4; ++jj) {
      const int gcol = n0 + wc + jj * 16 + lrow;
      const float bv = bias[gcol];
      #pragma unroll
      for (int r = 0; r < 4; ++r) {
        const int grow = m0 + wr + i * 16 + quad * 4 + r;
        float v = fmaxf(acc[i][jj][r] + bv, 0.f);       // relu
        Cb[(size_t)grow * D_ + gcol] = f2bf(v);
      }
    }
  }
}

// ---------------- embed dispatch: dupT + embed GEMM(x-direct) + qproj + cvt
#define DT2_BLKS 400
#define EG_BLKS  1200      // swz_grid(196, 6)
#define QP_BLKS  12
#define CV2_BLKS 256

struct EmbArgs {
  const float* x; const ushort* wembB; const float* b_embed; ushort* memB;
  const ushort* tgtB; const ushort* wqB;   const float* bq;      ushort* qB;
  const float* dup; ushort* dupT;
  const float* csrc[5]; ushort* cdst[5]; int cn4[5]; int ctotal;  // 8-float units
};

__global__ __launch_bounds__(256) void k_embed(EmbArgs ea) {
  __shared__ ushort As[2 * 64 * 32];
  __shared__ ushort Bs[2 * 128 * 32];
  int l = blockIdx.x;
  const int t = threadIdx.x;

  if (l < DT2_BLKS) {
    // dup_pool [g][d][f=97] -> dupT [g][f=112][d] bf16, f zero-padded.
    float (*tile)[33] = (float (*)[33])As;   // 4356 B, fits in As
    const int g = l >> 2, dchunk = l & 3;
    const int tx = t & 31, ty = t >> 5;
    for (int di = 0; di < 6; ++di) {
      const int d0 = dchunk * 192 + di * 32;
      for (int f0 = 0; f0 < 128; f0 += 32) {
        #pragma unroll
        for (int r = 0; r < 32; r += 8) {
          int d = d0 + ty + r, f = f0 + tx;
          tile[ty + r][tx] = (f < DF_) ? ea.dup[(size_t)g * D_ * DF_ + (size_t)d * DF_ + f] : 0.f;
        }
        __syncthreads();
        #pragma unroll
        for (int r = 0; r < 32; r += 8) {
          int f = f0 + ty + r, d = d0 + tx;
          if (f < FP_) ea.dupT[((size_t)g * FP_ + f) * D_ + d] = f2bf(tile[tx][ty + r]);
        }
        __syncthreads();
      }
    }
    return;
  }
  l -= DT2_BLKS;

  if (l < EG_BLKS) {
    const int mb = (l >> 3) / 6 * 8 + (l & 7);
    const int nb = (l >> 3) % 6;
    if (mb >= 196) return;
    gemm_core64_xa(ea.x, ea.wembB, ea.b_embed, ea.memB, mb * 64, nb * 128, As, Bs);
    return;
  }
  l -= EG_BLKS;

  if (l < QP_BLKS) {
    // qB[128][768] = tgtB @ wq^T + bq
    gemm_core64(ea.tgtB, ea.wqB, ea.bq, ea.qB, D_, D_, (l / 6) * 64, (l % 6) * 128, 0, As, Bs);
    return;
  }
  l -= QP_BLKS;

  // wk/wv/wo/w1/w2 fp32 -> bf16, grid-stride
  int i = l * 256 + t;
  const int stride = CV2_BLKS * 256;
  for (; i < ea.ctotal; i += stride) {
    int seg = 0, off = i;
    while (off >= ea.cn4[seg]) { off -= ea.cn4[seg]; ++seg; }
    const float4* sp = (const float4*)ea.csrc[seg];
    float4 v0 = sp[2 * off], v1 = sp[2 * off + 1];
    us8 o;
    o[0] = f2bf(v0.x); o[1] = f2bf(v0.y); o[2] = f2bf(v0.z); o[3] = f2bf(v0.w);
    o[4] = f2bf(v1.x); o[5] = f2bf(v1.y); o[6] = f2bf(v1.z); o[7] = f2bf(v1.w);
    ((us8*)ea.cdst[seg])[off] = o;
  }
}

// ---------------- fused attention: QK^T + softmax + PV ---------------------
__global__ __launch_bounds__(256) void k_attn(const ushort* __restrict__ qB,
    const ushort* __restrict__ Kb, const ushort* __restrict__ VbT, ushort* __restrict__ ctx) {
  __shared__ ushort lds[GP_ * SP_];   // 50176 B; first 39936 B doubles as K stage
  ushort* Ks = lds;
  ushort* Ps = lds;
  const int h = blockIdx.x, b = blockIdx.y, t = threadIdx.x;
  const int bh = b * NH_ + h;
  const int lane = t & 63, wave = t >> 6;
  const int quad = lane >> 4, c = lane & 15;
  for (int i = t; i < 208 * 12; i += 256) {
    int r = i / 12, col = (i % 12) * 8;
    gl2lds16(Kb + ((size_t)(b * S_ + r)) * D_ + h * HD_ + col, &Ks[i * 8]);
  }
  __syncthreads();
  const float scale = 0.1020620726f;  // 1/sqrt(96)
  f32x4 p[2][13];
  #pragma unroll
  for (int rep = 0; rep < 2; ++rep) {
    const int ii = wave + rep * 4;
    if (ii >= 7) continue;
    bf16x8 af[3];
    #pragma unroll
    for (int ks = 0; ks < 3; ++ks)
      af[ks] = *(const bf16x8*)(qB + ((size_t)(ii * 16 + c)) * D_ + h * HD_ + ks * 32 + quad * 8);
    __builtin_amdgcn_s_setprio(1);
    #pragma unroll
    for (int j = 0; j < 13; ++j) {
      f32x4 a = {};
      #pragma unroll
      for (int ks = 0; ks < 3; ++ks) {
        bf16x8 bf = *(const bf16x8*)&Ks[(j * 16 + c) * HD_ + ks * 32 + quad * 8];
        a = __builtin_amdgcn_mfma_f32_16x16x32_bf16(af[ks], bf, a, 0, 0, 0);
      }
      p[rep][j] = a;
    }
    __builtin_amdgcn_s_setprio(0);
    float m[4] = {-1e30f, -1e30f, -1e30f, -1e30f};
    #pragma unroll
    for (int j = 0; j < 13; ++j)
      #pragma unroll
      for (int r = 0; r < 4; ++r) {
        float v = p[rep][j][r] * scale;
        if (j == 12 && c >= 4) v = -1e30f;   // mask padded s 196..207 (kills NaN too)
        p[rep][j][r] = v;
        m[r] = fmaxf(m[r], v);
      }
    #pragma unroll
    for (int r = 0; r < 4; ++r) {
      m[r] = fmaxf(m[r], __shfl_xor(m[r], 1));
      m[r] = fmaxf(m[r], __shfl_xor(m[r], 2));
      m[r] = fmaxf(m[r], __shfl_xor(m[r], 4));
      m[r] = fmaxf(m[r], __shfl_xor(m[r], 8));
    }
    float lsum[4] = {0.f, 0.f, 0.f, 0.f};
    #pragma unroll
    for (int j = 0; j < 13; ++j)
      #pragma unroll
      for (int r = 0; r < 4; ++r) {
        float e = __expf(p[rep][j][r] - m[r]);
        p[rep][j][r] = e; lsum[r] += e;
      }
    #pragma unroll
    for (int r = 0; r < 4; ++r) {
      lsum[r] += __shfl_xor(lsum[r], 1);
      lsum[r] += __shfl_xor(lsum[r], 2);
      lsum[r] += __shfl_xor(lsum[r], 4);
      lsum[r] += __shfl_xor(lsum[r], 8);
      lsum[r] = 1.f / lsum[r];
    }
    #pragma unroll
    for (int j = 0; j < 13; ++j)
      #pragma unroll
      for (int r = 0; r < 4; ++r)
        p[rep][j][r] *= lsum[r];
  }
  __syncthreads();   // everyone done reading Ks -> safe to overwrite with Ps
  #pragma unroll
  for (int rep = 0; rep < 2; ++rep) {
    const int ii = wave + rep * 4;
    if (ii >= 7) continue;
    #pragma unroll
    for (int r = 0; r < 4; ++r) {
      const int g = ii * 16 + quad * 4 + r;
      #pragma unroll
      for (int j = 0; j < 13; ++j)
        Ps[g * SP_ + j * 16 + c] = f2bf(p[rep][j][r]);
      Ps[g * SP_ + 208 + c] = 0;   // pad s 208..223
    }
  }
  __syncthreads();
  #pragma unroll
  for (int rep = 0; rep < 2; ++rep) {
    const int ii = wave + rep * 4;
    if (ii >= 7) continue;
    bf16x8 af[7];
    #pragma unroll
    for (int k = 0; k < 7; ++k)
      af[k] = *(const bf16x8*)&Ps[(ii * 16 + c) * SP_ + k * 32 + quad * 8];
    #pragma unroll
    for (int j = 0; j < 6; ++j) {
      f32x4 acc = {};
      __builtin_amdgcn_s_setprio(1);
      #pragma unroll
      for (int k = 0; k < 7; ++k) {
        bf16x8 bf = *(const bf16x8*)(VbT + ((size_t)bh * HD_ + j * 16 + c) * SP_ + k * 32 + quad * 8);
        acc = __builtin_amdgcn_mfma_f32_16x16x32_bf16(af[k], bf, acc, 0, 0, 0);
      }
      __builtin_amdgcn_s_setprio(0);
      #pragma unroll
      for (int r = 0; r < 4; ++r) {
        const int g = ii * 16 + quad * 4 + r;
        if (g < G_)
          ctx[((size_t)(b * G_ + g)) * D_ + h * HD_ + j * 16 + c] = f2bf(acc[r]);
      }
    }
  }
}

// ---------------- residual + LayerNorm (add-input bf16) --------------------
// transb: bf16 out written transposed as [g][b][768] (for the head's A-operand)
__global__ __launch_bounds__(256) void k_lnres(const float* __restrict__ resid, int resid_mod,
    const ushort* __restrict__ addB, const float* __restrict__ gamma, const float* __restrict__ beta,
    float* __restrict__ outf, ushort* __restrict__ outb, int transb) {
  const int row = blockIdx.x, t = threadIdx.x;
  __shared__ float r1[256], r2[256];
  const float* rrow = resid + (size_t)(resid_mod ? (row % G_) : row) * D_;
  const ushort* arow = addB + (size_t)row * D_;
  float y[3]; float s = 0.f, sq = 0.f;
  #pragma unroll
  for (int i = 0; i < 3; ++i) {
    int d = t + i * 256;
    float v = rrow[d] + bf2f(arow[d]);
    y[i] = v; s += v; sq += v * v;
  }
  r1[t] = s; r2[t] = sq; __syncthreads();
  for (int o = 128; o > 0; o >>= 1) { if (t < o) { r1[t] += r1[t + o]; r2[t] += r2[t + o]; } __syncthreads(); }
  const float mean = r1[0] * (1.f / D_);
  const float var  = r2[0] * (1.f / D_) - mean * mean;
  const float w = rsqrtf(var + 1e-5f);
  const size_t orow = transb ? ((size_t)(row % G_) * B_ + row / G_) : (size_t)row;
  #pragma unroll
  for (int i = 0; i < 3; ++i) {
    int d = t + i * 256;
    float v = (y[i] - mean) * w * gamma[d] + beta[d];
    if (outf) outf[(size_t)row * D_ + d] = v;
    if (outb) outb[orow * D_ + d] = f2bf(v);
  }
}

// ---------------- grouped head via MFMA, LDS-free, coalesced ---------------
__global__ __launch_bounds__(256) void k_head4(const ushort* __restrict__ hT,
    const ushort* __restrict__ dupT, const float* __restrict__ dup_bias, float* __restrict__ out) {
  const int g = blockIdx.x, j = blockIdx.y, t = threadIdx.x;
  const int lane = t & 63, wave = t >> 6;
  const int quad = lane >> 4, c = lane & 15;
  const ushort* ap = hT + ((size_t)g * B_ + wave * 16 + c) * D_;
  const ushort* bp = dupT + ((size_t)g * FP_ + j * 16 + c) * D_;
  f32x4 acc = {};
  #pragma unroll 8
  for (int k0 = 0; k0 < D_; k0 += 32) {
    bf16x8 af = *(const bf16x8*)(ap + k0 + quad * 8);
    bf16x8 bf = *(const bf16x8*)(bp + k0 + quad * 8);
    acc = __builtin_amdgcn_mfma_f32_16x16x32_bf16(af, bf, acc, 0, 0, 0);
  }
  const int f = j * 16 + c;
  if (f >= DF_) return;
  const int n = g * DF_ + f;
  if (n >= NC_) return;
  const float bv = dup_bias[n];
  #pragma unroll
  for (int r = 0; r < 4; ++r) {
    const int b = wave * 16 + quad * 4 + r;
    out[(size_t)b * NC_ + n] = acc[r] + bv;
  }
}

// ---------------------------------------------------------------------------
// workspace layout (bytes)
// ---------------------------------------------------------------------------
static constexpr size_t OFF_VBT   = 0;          // bf16 [512,96,224]  = 22,020,096
static constexpr size_t OFF_FF    = 0;          // bf16 [6400,2048] = 26,214,400
static constexpr size_t OFF_FFO   = 26214400;   // bf16 [6400,768]  = 9,830,400 (end 36,044,800)
static constexpr size_t OFF_WEMB  = 51380224;   // bf16 3,145,728
static constexpr size_t OFF_MEM   = 54525952;   // bf16 [12544,768] = 19,267,584
static constexpr size_t OFF_WK    = 73793536;   // 1,179,648   (wk|wv contiguous = fused 1536x768)
static constexpr size_t OFF_WV    = 74973184;   // 1,179,648
static constexpr size_t OFF_WO    = 76152832;   // 1,179,648
static constexpr size_t OFF_W1    = 77332480;   // 3,145,728
static constexpr size_t OFF_W2    = 80478208;   // 3,145,728
static constexpr size_t OFF_DUP   = 83623936;   // bf16 [100,112,768] = 17,203,200
static constexpr size_t OFF_KB    = 100827136;  // bf16 [12544,768] = 19,267,584
static constexpr size_t OFF_TGT   = 139362304;  // f32 [100,768] = 307,200
static constexpr size_t OFF_TGTB  = 139669504;  // bf16 [128,768] = 196,608
static constexpr size_t OFF_Q     = 139866112;  // bf16 [128,768] = 196,608
static constexpr size_t OFF_CTX   = 140068864;  // bf16 9,830,400 (also wqB early: dead before attn)
static constexpr size_t OFF_WQ    = OFF_CTX;    // bf16 [768,768] = 1,179,648 (consumed before ctx written)
static constexpr size_t OFF_CTXO  = 149899264;  // bf16 [6400,768] = 9,830,400
static constexpr size_t OFF_TGT2F = 169560064;  // f32 19,660,800
static constexpr size_t OFF_TGT2B = 189220864;  // bf16 9,830,400
static constexpr size_t OFF_HB    = 199051264;  // bf16 [100,64,768] = 9,830,400 (end 208,881,664)

extern "C" void kernel_launch(void* const* d_in, const int* in_sizes, int n_in,
                              void* d_out, int out_size, void* d_ws, size_t ws_size,
                              hipStream_t stream) {
  const float* x           = (const float*)d_in[0];
  const float* w_embed     = (const float*)d_in[1];
  const float* b_embed     = (const float*)d_in[2];
  const float* query_embed = (const float*)d_in[3];
  const float* wq          = (const float*)d_in[4];
  const float* bq          = (const float*)d_in[5];
  const float* wk          = (const float*)d_in[6];
  const float* bk          = (const float*)d_in[7];
  const float* wv          = (const float*)d_in[8];
  const float* bv          = (const float*)d_in[9];
  const float* wo          = (const float*)d_in[10];
  const float* bo          = (const float*)d_in[11];
  const float* g1          = (const float*)d_in[12];
  const float* be1         = (const float*)d_in[13];
  const float* g2          = (const float*)d_in[14];
  const float* be2         = (const float*)d_in[15];
  const float* g3          = (const float*)d_in[16];
  const float* be3         = (const float*)d_in[17];
  const float* w1          = (const float*)d_in[18];
  const float* bl1         = (const float*)d_in[19];
  const float* w2          = (const float*)d_in[20];
  const float* bl2         = (const float*)d_in[21];
  const float* dup_pool    = (const float*)d_in[22];
  const float* dup_bias    = (const float*)d_in[23];
  float* out = (float*)d_out;
  char* ws = (char*)d_ws;

  ushort* wembB = (ushort*)(ws + OFF_WEMB);
  ushort* memB  = (ushort*)(ws + OFF_MEM);
  ushort* wkvB  = (ushort*)(ws + OFF_WK);    // fused [1536][768]
  ushort* wkB   = (ushort*)(ws + OFF_WK);
  ushort* wvB   = (ushort*)(ws + OFF_WV);
  ushort* woB   = (ushort*)(ws + OFF_WO);
  ushort* w1B   = (ushort*)(ws + OFF_W1);
  ushort* w2B   = (ushort*)(ws + OFF_W2);
  ushort* wqB   = (ushort*)(ws + OFF_WQ);
  ushort* dupT  = (ushort*)(ws + OFF_DUP);
  ushort* Kb    = (ushort*)(ws + OFF_KB);
  float*  tgtF  = (float*)(ws + OFF_TGT);
  ushort* tgtB  = (ushort*)(ws + OFF_TGTB);
  ushort* qB    = (ushort*)(ws + OFF_Q);
  ushort* VbT   = (ushort*)(ws + OFF_VBT);
  ushort* ctxB  = (ushort*)(ws + OFF_CTX);
  ushort* ctxoB = (ushort*)(ws + OFF_CTXO);
  float*  tgt2F = (float*)(ws + OFF_TGT2F);
  ushort* tgt2B = (ushort*)(ws + OFF_TGT2B);
  ushort* ffB   = (ushort*)(ws + OFF_FF);
  ushort* ffoB  = (ushort*)(ws + OFF_FFO);
  ushort* hT    = (ushort*)(ws + OFF_HB);

  // 1. prep (tiny): wemb/wq cvt + tgt LN
  PrepArgs pa;
  pa.csrc[0] = w_embed; pa.cdst[0] = wembB; pa.cn4[0] = D_ * CIN_ / 8;
  pa.csrc[1] = wq;      pa.cdst[1] = wqB;   pa.cn4[1] = D_ * D_ / 8;
  pa.ctotal = pa.cn4[0] + pa.cn4[1];
  pa.qe = query_embed; pa.g1 = g1; pa.be1 = be1; pa.tgt = tgtF; pa.tgtB = tgtB;
  k_prep<<<CVP_BLKS + TG_BLKS, 256, 0, stream>>>(pa);

  // 2. embed dispatch: dupT + embed GEMM (A straight from x, +relu) + q-proj
  //    + wk/wv/wo/w1/w2 cvt
  EmbArgs ea;
  ea.x = x; ea.wembB = wembB; ea.b_embed = b_embed; ea.memB = memB;
  ea.tgtB = tgtB; ea.wqB = wqB; ea.bq = bq; ea.qB = qB;
  ea.dup = dup_pool; ea.dupT = dupT;
  ea.csrc[0] = wk; ea.cdst[0] = wkB; ea.cn4[0] = D_ * D_ / 8;
  ea.csrc[1] = wv; ea.cdst[1] = wvB; ea.cn4[1] = D_ * D_ / 8;
  ea.csrc[2] = wo; ea.cdst[2] = woB; ea.cn4[2] = D_ * D_ / 8;
  ea.csrc[3] = w1; ea.cdst[3] = w1B; ea.cn4[3] = FF_ * D_ / 8;
  ea.csrc[4] = w2; ea.cdst[4] = w2B; ea.cn4[4] = D_ * FF_ / 8;
  ea.ctotal = ea.cn4[0] + ea.cn4[1] + ea.cn4[2] + ea.cn4[3] + ea.cn4[4];
  k_embed<<<DT2_BLKS + EG_BLKS + QP_BLKS + CV2_BLKS, 256, 0, stream>>>(ea);

  // 3. fused K|V projection: K -> Kb [12544,768], V -> VbT [512][96][224] transposed
  k_gemm<<<swz_grid(98, 12), 256, 0, stream>>>(memB, wkvB, bk, bv, nullptr, Kb, VbT,
                                               D_, D_, 12, 98, 0);

  // 4. fused attention (QK^T + softmax + PV)
  k_attn<<<dim3(NH_, B_), 256, 0, stream>>>(qB, Kb, VbT, ctxB);

  // 5. ctx @ wo^T + bo -> bf16 [6400, 768] (64-row tiles)
  k_gemm64<<<swz_grid(100, 6), 256, 0, stream>>>(ctxB, woB, bo, ctxoB, D_, D_, 6, 100, 0);

  // 6. tgt2 = LN(tgt + ctxo)
  k_lnres<<<BG_, 256, 0, stream>>>(tgtF, 1, ctxoB, g2, be2, tgt2F, tgt2B, 0);

  // 7-8. FFN
  k_gemm<<<swz_grid(50, 16), 256, 0, stream>>>(tgt2B, w1B, bl1, nullptr, nullptr, ffB, nullptr,
                                               FF_, D_, 16, 50, 1);
  k_gemm64<<<swz_grid(100, 6), 256, 0, stream>>>(ffB, w2B, bl2, ffoB, D_, FF_, 6, 100, 0);

  // 9. h = LN(tgt2 + ffo) -> bf16 transposed [g][64][768]
  k_lnres<<<BG_, 256, 0, stream>>>(tgt2F, 0, ffoB, g3, be3, nullptr, hT, 1);

  // 10. grouped head -> logits fp32 [64, 9605] via MFMA (coalesced, LDS-free)
  k_head4<<<dim3(G_, 7), 256, 0, stream>>>(hT, dupT, dup_bias, out);
}

// Round 7
// 578.001 us; speedup vs baseline: 1.0365x; 1.0365x over previous
//
#include <hip/hip_runtime.h>
#include <hip/hip_bf16.h>

// ---------------------------------------------------------------------------
// MLDecoder classification head, MI355X bf16-MFMA implementation.
// B=64, C_IN=2048, H=W=14 (S=196), D=768, FF=2048, G=100, NC=9605, NH=8, HD=96
// ---------------------------------------------------------------------------

#define B_    64
#define CIN_  2048
#define S_    196
#define D_    768
#define FF_   2048
#define G_    100
#define NC_   9605
#define NH_   8
#define HD_   96
#define DF_   97
#define FP_   112          // DF_ padded to 16
#define GP_   112          // G padded to 16
#define SP_   224          // S padded to 32 (7 K-steps) for P / V^T
#define BS_   (B_ * S_)   // 12544
#define BG_   (B_ * G_)   // 6400

typedef __bf16 bf16x8 __attribute__((ext_vector_type(8)));
typedef float  f32x4  __attribute__((ext_vector_type(4)));
typedef ushort us8    __attribute__((ext_vector_type(8)));

__device__ __forceinline__ float bf2f(ushort u) {
  union { unsigned int i; float f; } v; v.i = ((unsigned int)u) << 16; return v.f;
}
__device__ __forceinline__ ushort f2bf(float f) {
  __hip_bfloat16 h = __float2bfloat16(f);
  return *reinterpret_cast<ushort*>(&h);
}

// async global->LDS, 16 bytes per lane. LDS target must be wave-uniform base
// + lane*16 (our staging layouts satisfy this: lds byte offset == 16*i, i linear in t).
__device__ __forceinline__ void gl2lds16(const ushort* g, ushort* l) {
  __builtin_amdgcn_global_load_lds((const __attribute__((address_space(1))) unsigned int*)g,
                                   (__attribute__((address_space(3))) unsigned int*)l, 16, 0, 0);
}

// ---------------------------------------------------------------------------
// k_prep (R14): TINY — only wemb/wq converts + tgt LN. x-transpose gone:
// the embed GEMM reads x directly (R14 fixed A-path; R13's version had a
// 16-way LDS write conflict, single-buffering and 2-wave staging — 43M
// SQ_LDS_BANK_CONFLICT, 193us).
// ---------------------------------------------------------------------------
#define CVP_BLKS 1024   // cvt: wemb + wq, grid-stride, 8-float units
#define TG_BLKS  128    // tgt LN rows (padded)

struct PrepArgs {
  const float* csrc[2]; ushort* cdst[2]; int cn4[2]; int ctotal;  // 8-float units
  const float* qe; const float* g1; const float* be1;
  float* tgt; ushort* tgtB;
};

__global__ __launch_bounds__(256) void k_prep(PrepArgs pa) {
  __shared__ float r1[256], r2[256];
  int jid = blockIdx.x;
  const int t = threadIdx.x;

  if (jid < CVP_BLKS) {
    // wemb + wq fp32 -> bf16, 8 floats per unit.
    int i = jid * 256 + t;
    const int stride = CVP_BLKS * 256;
    for (; i < pa.ctotal; i += stride) {
      int seg = 0, off = i;
      while (off >= pa.cn4[seg]) { off -= pa.cn4[seg]; ++seg; }
      const float4* sp = (const float4*)pa.csrc[seg];
      float4 v0 = sp[2 * off], v1 = sp[2 * off + 1];
      us8 o;
      o[0] = f2bf(v0.x); o[1] = f2bf(v0.y); o[2] = f2bf(v0.z); o[3] = f2bf(v0.w);
      o[4] = f2bf(v1.x); o[5] = f2bf(v1.y); o[6] = f2bf(v1.z); o[7] = f2bf(v1.w);
      ((us8*)pa.cdst[seg])[off] = o;
    }
    return;
  }
  jid -= CVP_BLKS;

  // tgt = LN(2*query_embed)*g1 + be1 -> fp32 [100,768] + bf16 [128,768] (pad 0)
  const int g = jid;
  if (g >= G_) {
    for (int d = t; d < D_; d += 256) pa.tgtB[(size_t)g * D_ + d] = 0;
    return;
  }
  float y[3]; float s = 0.f, sq = 0.f;
  const float* row = pa.qe + (size_t)g * D_;
  #pragma unroll
  for (int i = 0; i < 3; ++i) { float v = 2.f * row[t + i * 256]; y[i] = v; s += v; sq += v * v; }
  r1[t] = s; r2[t] = sq; __syncthreads();
  for (int o = 128; o > 0; o >>= 1) { if (t < o) { r1[t] += r1[t + o]; r2[t] += r2[t + o]; } __syncthreads(); }
  const float mean = r1[0] * (1.f / D_);
  const float var  = r2[0] * (1.f / D_) - mean * mean;
  const float w = rsqrtf(var + 1e-5f);
  #pragma unroll
  for (int i = 0; i < 3; ++i) {
    int d = t + i * 256;
    float v = (y[i] - mean) * w * pa.g1[d] + pa.be1[d];
    pa.tgt[(size_t)g * D_ + d] = v;
    pa.tgtB[(size_t)g * D_ + d] = f2bf(v);
  }
}

// ---------------- bf16 MFMA GEMM core: C[M,N] = A[M,K]*B[N,K]^T + bias -----
// 128x128 tile, BK=32, counted-vmcnt two-barrier k-loop (R11).
// KV mode (Vt != null): cols >= 768 are the V projection, written TRANSPOSED
// into VbT [bh][hd][s].
__device__ __forceinline__ void gemm_core(const ushort* __restrict__ A, const ushort* __restrict__ B,
    const float* __restrict__ bias, const float* __restrict__ bias2,
    float* __restrict__ Cf, ushort* __restrict__ Cb, ushort* __restrict__ Vt,
    int N, int K, int m0, int n0, int relu, ushort* As, ushort* Bs) {
  const int t = threadIdx.x;
  const int lane = t & 63, wave = t >> 6;
  const int quad = lane >> 4, lrow = lane & 15;
  const int wr = (wave >> 1) * 64, wc = (wave & 1) * 64;
  const int srow = t >> 2, scol = (t & 3) * 8;
  const ushort* ag = A + (size_t)(m0 + srow) * K + scol;
  const ushort* bg = B + (size_t)(n0 + srow) * K + scol;
  ushort* asw = As + t * 8;   // linear dest: byte 16*t within buffer
  ushort* bsw = Bs + t * 8;
  f32x4 acc[4][4] = {};
  gl2lds16(ag,                  asw);
  gl2lds16(ag + (size_t)64 * K, asw + 64 * 32);
  gl2lds16(bg,                  bsw);
  gl2lds16(bg + (size_t)64 * K, bsw + 64 * 32);
  int cur = 0;
  for (int k0 = 0; k0 < K; k0 += 32) {
    if (k0 + 32 < K) {                      // prefetch next k-step into other buf
      const int nb = (cur ^ 1) * (128 * 32);
      gl2lds16(ag + k0 + 32,                  asw + nb);
      gl2lds16(ag + k0 + 32 + (size_t)64 * K, asw + nb + 64 * 32);
      gl2lds16(bg + k0 + 32,                  bsw + nb);
      gl2lds16(bg + k0 + 32 + (size_t)64 * K, bsw + nb + 64 * 32);
      asm volatile("s_waitcnt vmcnt(4)" ::: "memory");   // cur staged; prefetch flying
    } else {
      asm volatile("s_waitcnt vmcnt(0)" ::: "memory");
    }
    __builtin_amdgcn_s_barrier();
    __builtin_amdgcn_sched_barrier(0);
    const ushort* as = As + cur * (128 * 32);
    const ushort* bs = Bs + cur * (128 * 32);
    bf16x8 af[4], bfr[4];
    #pragma unroll
    for (int i = 0; i < 4; ++i) af[i] = *(const bf16x8*)&as[(wr + i * 16 + lrow) * 32 + quad * 8];
    #pragma unroll
    for (int j = 0; j < 4; ++j) bfr[j] = *(const bf16x8*)&bs[(wc + j * 16 + lrow) * 32 + quad * 8];
    __builtin_amdgcn_s_setprio(1);
    #pragma unroll
    for (int i = 0; i < 4; ++i)
      #pragma unroll
      for (int j = 0; j < 4; ++j)
        acc[i][j] = __builtin_amdgcn_mfma_f32_16x16x32_bf16(af[i], bfr[j], acc[i][j], 0, 0, 0);
    __builtin_amdgcn_s_setprio(0);
    __builtin_amdgcn_sched_barrier(0);
    __builtin_amdgcn_s_barrier();           // all done reading cur -> safe to overwrite
    __builtin_amdgcn_sched_barrier(0);
    cur ^= 1;
  }
  #pragma unroll
  for (int i = 0; i < 4; ++i) {
    #pragma unroll
    for (int j = 0; j < 4; ++j) {
      const int gcol = n0 + wc + j * 16 + lrow;
      const float bv = (bias2 && gcol >= D_) ? bias2[gcol - D_] : (bias ? bias[gcol] : 0.f);
      if (Vt && gcol >= D_) {
        const int dv = gcol - D_, hh = dv / HD_, hd = dv % HD_;
        const int row0 = m0 + wr + i * 16 + quad * 4;
        const int bb = row0 / S_, ss = row0 % S_;
        ushort4 o;
        o.x = f2bf(acc[i][j][0] + bv);
        o.y = f2bf(acc[i][j][1] + bv);
        o.z = f2bf(acc[i][j][2] + bv);
        o.w = f2bf(acc[i][j][3] + bv);
        *(ushort4*)&Vt[((size_t)(bb * NH_ + hh) * HD_ + hd) * SP_ + ss] = o;
      } else {
        #pragma unroll
        for (int r = 0; r < 4; ++r) {
          const int grow = m0 + wr + i * 16 + quad * 4 + r;
          float v = acc[i][j][r] + bv;
          if (relu) v = fmaxf(v, 0.f);
          if (Cf) Cf[(size_t)grow * N + gcol] = v;
          else    Cb[(size_t)grow * N + gcol] = f2bf(v);
        }
      }
    }
  }
}

__global__ __launch_bounds__(256) void k_gemm(const ushort* __restrict__ A, const ushort* __restrict__ B,
    const float* __restrict__ bias, const float* __restrict__ bias2,
    float* __restrict__ Cf, ushort* __restrict__ Cb, ushort* __restrict__ Vt,
    int N, int K, int nbx, int nm, int relu) {
  __shared__ ushort As[2 * 128 * 32];
  __shared__ ushort Bs[2 * 128 * 32];
  const int l = blockIdx.x;
  const int mb = (l >> 3) / nbx * 8 + (l & 7);
  const int nb = (l >> 3) % nbx;
  if (mb >= nm) return;
  gemm_core(A, B, bias, bias2, Cf, Cb, Vt, N, K, mb * 128, nb * 128, relu, As, Bs);
}
static inline int swz_grid(int nm, int nbx) { return ((nm + 7) & ~7) * nbx; }

// ---------------- 64x128-tile GEMM core (R9/R11) ---------------------------
__device__ __forceinline__ void gemm_core64(const ushort* __restrict__ A, const ushort* __restrict__ B,
    const float* __restrict__ bias, ushort* __restrict__ Cb,
    int N, int K, int m0, int n0, int relu, ushort* As, ushort* Bs) {
  const int t = threadIdx.x;
  const int lane = t & 63, wave = t >> 6;
  const int quad = lane >> 4, lrow = lane & 15;
  const int wr = (wave >> 1) * 32, wc = (wave & 1) * 64;
  const int srow = t >> 2, scol = (t & 3) * 8;
  const ushort* ag = A + (size_t)(m0 + srow) * K + scol;
  const ushort* bg = B + (size_t)(n0 + srow) * K + scol;
  ushort* asw = As + t * 8;
  ushort* bsw = Bs + t * 8;
  f32x4 acc[2][4] = {};
  gl2lds16(ag,                  asw);
  gl2lds16(bg,                  bsw);
  gl2lds16(bg + (size_t)64 * K, bsw + 64 * 32);
  int cur = 0;
  for (int k0 = 0; k0 < K; k0 += 32) {
    if (k0 + 32 < K) {
      gl2lds16(ag + k0 + 32,                  asw + (cur ^ 1) * (64 * 32));
      gl2lds16(bg + k0 + 32,                  bsw + (cur ^ 1) * (128 * 32));
      gl2lds16(bg + k0 + 32 + (size_t)64 * K, bsw + (cur ^ 1) * (128 * 32) + 64 * 32);
      asm volatile("s_waitcnt vmcnt(3)" ::: "memory");
    } else {
      asm volatile("s_waitcnt vmcnt(0)" ::: "memory");
    }
    __builtin_amdgcn_s_barrier();
    __builtin_amdgcn_sched_barrier(0);
    const ushort* as = As + cur * (64 * 32);
    const ushort* bs = Bs + cur * (128 * 32);
    bf16x8 af[2], bfr[4];
    #pragma unroll
    for (int i = 0; i < 2; ++i) af[i] = *(const bf16x8*)&as[(wr + i * 16 + lrow) * 32 + quad * 8];
    #pragma unroll
    for (int j = 0; j < 4; ++j) bfr[j] = *(const bf16x8*)&bs[(wc + j * 16 + lrow) * 32 + quad * 8];
    __builtin_amdgcn_s_setprio(1);
    #pragma unroll
    for (int i = 0; i < 2; ++i)
      #pragma unroll
      for (int j = 0; j < 4; ++j)
        acc[i][j] = __builtin_amdgcn_mfma_f32_16x16x32_bf16(af[i], bfr[j], acc[i][j], 0, 0, 0);
    __builtin_amdgcn_s_setprio(0);
    __builtin_amdgcn_sched_barrier(0);
    __builtin_amdgcn_s_barrier();
    __builtin_amdgcn_sched_barrier(0);
    cur ^= 1;
  }
  #pragma unroll
  for (int i = 0; i < 2; ++i) {
    #pragma unroll
    for (int j = 0; j < 4; ++j) {
      const int gcol = n0 + wc + j * 16 + lrow;
      const float bv = bias ? bias[gcol] : 0.f;
      #pragma unroll
      for (int r = 0; r < 4; ++r) {
        const int grow = m0 + wr + i * 16 + quad * 4 + r;
        float v = acc[i][j][r] + bv;
        if (relu) v = fmaxf(v, 0.f);
        Cb[(size_t)grow * N + gcol] = f2bf(v);
      }
    }
  }
}

__global__ __launch_bounds__(256) void k_gemm64(const ushort* __restrict__ A, const ushort* __restrict__ B,
    const float* __restrict__ bias, ushort* __restrict__ Cb,
    int N, int K, int nbx, int nm, int relu) {
  __shared__ ushort As[2 * 64 * 32];
  __shared__ ushort Bs[2 * 128 * 32];
  const int l = blockIdx.x;
  const int mb = (l >> 3) / nbx * 8 + (l & 7);
  const int nb = (l >> 3) % nbx;
  if (mb >= nm) return;
  gemm_core64(A, B, bias, Cb, N, K, mb * 64, nb * 128, relu, As, Bs);
}

// ---------------- 64x128 embed core, A read DIRECTLY from x (R14) ----------
// A[row][c] = x[b][c][s], row=(b,s). ALL 256 threads stage A: thread
// (j=t&15, q=t>>4) loads 2 float4 along s (16 lanes x 16B = 256B contiguous
// per c-row) and writes 4 ushort2 into a DOUBLY-XOR-swizzled A-tile:
//   physical row  prow = row ^ ((row>>4)&1)           (row-level XOR, bit6)
//   16B block     blk' = blk ^ ((row>>2)&3)           (block-level XOR)
// -> ds_write banks 2-way (free; R13's linear layout was 16-way = 43M
// conflicts), b128 reads stay 16B-aligned and 2-way.
// Counted-vmcnt double-buffered protocol (FIFO-verified):
//   top:    issue A(t+1)->regs, B(t+1)->Bs[c^1]; vmcnt(4) drains B(t);
//           lgkmcnt(0) publishes our A ds_writes; barrier
//   mid:    ds_read + 8 MFMA (setprio)
//   bottom: barrier; vmcnt(2) drains A(t+1) regs; ds_write -> As[c^1]
__device__ __forceinline__ void gemm_core64_xa(const float* __restrict__ X,
    const ushort* __restrict__ Bw, const float* __restrict__ bias, ushort* __restrict__ Cb,
    int m0, int n0, ushort* As, ushort* Bs) {
  const int t = threadIdx.x;
  const int lane = t & 63, wave = t >> 6;
  const int quad = lane >> 4, lrow = lane & 15;
  const int wr = (wave >> 1) * 32, wc = (wave & 1) * 64;
  // A staging: j = s-quad (0..15), q = c-pair (0..15)
  const int j = t & 15, q = t >> 4;
  const int arow = m0 + 4 * j;                    // 196%4==0: 4-row group single-b
  const float* px = X + ((size_t)(arow / S_) * CIN_ + 2 * q) * S_ + (arow % S_);
  const int ablk = (((q >> 2) ^ (j & 3)) << 3) + 2 * (q & 3);  // ushort offset in row
  const int rxor = (j >> 2) & 1;                  // row-level XOR key (row>>4 == j>>2)
  // B staging (linear, gl2lds)
  const ushort* bg = Bw + (size_t)(n0 + (t >> 2)) * CIN_ + (t & 3) * 8;
  ushort* bsw = Bs + t * 8;
  f32x4 acc[2][4] = {};
  float4 a0, a1;
  // prologue (k-step 0)
  a0 = *(const float4*)(px);
  a1 = *(const float4*)(px + S_);
  gl2lds16(bg,                     bsw);
  gl2lds16(bg + (size_t)64 * CIN_, bsw + 64 * 32);
  asm volatile("s_waitcnt vmcnt(2)" ::: "memory");     // a0,a1 loaded; B(0) flying
  #pragma unroll
  for (int r = 0; r < 4; ++r) {
    ushort2 o = { f2bf(((const float*)&a0)[r]), f2bf(((const float*)&a1)[r]) };
    *(ushort2*)&As[(((4 * j + r) ^ rxor) * 32) + ablk] = o;
  }
  const int NK = CIN_ / 32;   // 64 k-steps
  for (int tk = 0; tk < NK; ++tk) {
    const int c = tk & 1;
    if (tk + 1 < NK) {
      const float* pn = px + (size_t)(tk + 1) * 32 * S_;
      a0 = *(const float4*)(pn);
      a1 = *(const float4*)(pn + S_);
      const ushort* bn = bg + (tk + 1) * 32;
      gl2lds16(bn,                     bsw + (c ^ 1) * (128 * 32));
      gl2lds16(bn + (size_t)64 * CIN_, bsw + (c ^ 1) * (128 * 32) + 64 * 32);
      asm volatile("s_waitcnt vmcnt(4) lgkmcnt(0)" ::: "memory");  // B(t) done; A writes visible
    } else {
      asm volatile("s_waitcnt vmcnt(0) lgkmcnt(0)" ::: "memory");
    }
    __builtin_amdgcn_s_barrier();
    __builtin_amdgcn_sched_barrier(0);
    const ushort* as = As + c * (64 * 32);
    const ushort* bs = Bs + c * (128 * 32);
    bf16x8 af[2], bfr[4];
    #pragma unroll
    for (int i = 0; i < 2; ++i) {
      const int R = wr + i * 16 + lrow;
      af[i] = *(const bf16x8*)&as[((R ^ ((R >> 4) & 1)) * 32) + ((quad ^ ((R >> 2) & 3)) << 3)];
    }
    #pragma unroll
    for (int jj = 0; jj < 4; ++jj)
      bfr[jj] = *(const bf16x8*)&bs[(wc + jj * 16 + lrow) * 32 + quad * 8];
    __builtin_amdgcn_s_setprio(1);
    #pragma unroll
    for (int i = 0; i < 2; ++i)
      #pragma unroll
      for (int jj = 0; jj < 4; ++jj)
        acc[i][jj] = __builtin_amdgcn_mfma_f32_16x16x32_bf16(af[i], bfr[jj], acc[i][jj], 0, 0, 0);
    __builtin_amdgcn_s_setprio(0);
    __builtin_amdgcn_sched_barrier(0);
    __builtin_amdgcn_s_barrier();           // all waves done reading buffers c
    __builtin_amdgcn_sched_barrier(0);
    if (tk + 1 < NK) {
      asm volatile("s_waitcnt vmcnt(2)" ::: "memory");  // A(t+1) regs ready (B(t+1) may fly)
      #pragma unroll
      for (int r = 0; r < 4; ++r) {
        ushort2 o = { f2bf(((const float*)&a0)[r]), f2bf(((const float*)&a1)[r]) };
        *(ushort2*)&As[(c ^ 1) * (64 * 32) + (((4 * j + r) ^ rxor) * 32) + ablk] = o;
      }
    }
  }
  #pragma unroll
  for (int i = 0; i < 2; ++i) {
    #pragma unroll
    for (int jj = 0; jj < 4; ++jj) {
      const int gcol = n0 + wc + jj * 16 + lrow;
      const float bv = bias[gcol];
      #pragma unroll
      for (int r = 0; r < 4; ++r) {
        const int grow = m0 + wr + i * 16 + quad * 4 + r;
        float v = fmaxf(acc[i][jj][r] + bv, 0.f);       // relu
        Cb[(size_t)grow * D_ + gcol] = f2bf(v);
      }
    }
  }
}

// ---------------- embed dispatch: dupT + embed GEMM(x-direct) + qproj + cvt
#define DT2_BLKS 400
#define EG_BLKS  1200      // swz_grid(196, 6)
#define QP_BLKS  12
#define CV2_BLKS 256

struct EmbArgs {
  const float* x; const ushort* wembB; const float* b_embed; ushort* memB;
  const ushort* tgtB; const ushort* wqB;   const float* bq;      ushort* qB;
  const float* dup; ushort* dupT;
  const float* csrc[5]; ushort* cdst[5]; int cn4[5]; int ctotal;  // 8-float units
};

__global__ __launch_bounds__(256) void k_embed(EmbArgs ea) {
  __shared__ ushort As[2 * 64 * 32];
  __shared__ ushort Bs[2 * 128 * 32];
  int l = blockIdx.x;
  const int t = threadIdx.x;

  if (l < DT2_BLKS) {
    // dup_pool [g][d][f=97] -> dupT [g][f=112][d] bf16, f zero-padded.
    float (*tile)[33] = (float (*)[33])As;   // 4356 B, fits in As
    const int g = l >> 2, dchunk = l & 3;
    const int tx = t & 31, ty = t >> 5;
    for (int di = 0; di < 6; ++di) {
      const int d0 = dchunk * 192 + di * 32;
      for (int f0 = 0; f0 < 128; f0 += 32) {
        #pragma unroll
        for (int r = 0; r < 32; r += 8) {
          int d = d0 + ty + r, f = f0 + tx;
          tile[ty + r][tx] = (f < DF_) ? ea.dup[(size_t)g * D_ * DF_ + (size_t)d * DF_ + f] : 0.f;
        }
        __syncthreads();
        #pragma unroll
        for (int r = 0; r < 32; r += 8) {
          int f = f0 + ty + r, d = d0 + tx;
          if (f < FP_) ea.dupT[((size_t)g * FP_ + f) * D_ + d] = f2bf(tile[tx][ty + r]);
        }
        __syncthreads();
      }
    }
    return;
  }
  l -= DT2_BLKS;

  if (l < EG_BLKS) {
    const int mb = (l >> 3) / 6 * 8 + (l & 7);
    const int nb = (l >> 3) % 6;
    if (mb >= 196) return;
    gemm_core64_xa(ea.x, ea.wembB, ea.b_embed, ea.memB, mb * 64, nb * 128, As, Bs);
    return;
  }
  l -= EG_BLKS;

  if (l < QP_BLKS) {
    // qB[128][768] = tgtB @ wq^T + bq
    gemm_core64(ea.tgtB, ea.wqB, ea.bq, ea.qB, D_, D_, (l / 6) * 64, (l % 6) * 128, 0, As, Bs);
    return;
  }
  l -= QP_BLKS;

  // wk/wv/wo/w1/w2 fp32 -> bf16, grid-stride
  int i = l * 256 + t;
  const int stride = CV2_BLKS * 256;
  for (; i < ea.ctotal; i += stride) {
    int seg = 0, off = i;
    while (off >= ea.cn4[seg]) { off -= ea.cn4[seg]; ++seg; }
    const float4* sp = (const float4*)ea.csrc[seg];
    float4 v0 = sp[2 * off], v1 = sp[2 * off + 1];
    us8 o;
    o[0] = f2bf(v0.x); o[1] = f2bf(v0.y); o[2] = f2bf(v0.z); o[3] = f2bf(v0.w);
    o[4] = f2bf(v1.x); o[5] = f2bf(v1.y); o[6] = f2bf(v1.z); o[7] = f2bf(v1.w);
    ((us8*)ea.cdst[seg])[off] = o;
  }
}

// ---------------- fused attention: QK^T + softmax + PV ---------------------
__global__ __launch_bounds__(256) void k_attn(const ushort* __restrict__ qB,
    const ushort* __restrict__ Kb, const ushort* __restrict__ VbT, ushort* __restrict__ ctx) {
  __shared__ ushort lds[GP_ * SP_];   // 50176 B; first 39936 B doubles as K stage
  ushort* Ks = lds;
  ushort* Ps = lds;
  const int h = blockIdx.x, b = blockIdx.y, t = threadIdx.x;
  const int bh = b * NH_ + h;
  const int lane = t & 63, wave = t >> 6;
  const int quad = lane >> 4, c = lane & 15;
  for (int i = t; i < 208 * 12; i += 256) {
    int r = i / 12, col = (i % 12) * 8;
    gl2lds16(Kb + ((size_t)(b * S_ + r)) * D_ + h * HD_ + col, &Ks[i * 8]);
  }
  __syncthreads();
  const float scale = 0.1020620726f;  // 1/sqrt(96)
  f32x4 p[2][13];
  #pragma unroll
  for (int rep = 0; rep < 2; ++rep) {
    const int ii = wave + rep * 4;
    if (ii >= 7) continue;
    bf16x8 af[3];
    #pragma unroll
    for (int ks = 0; ks < 3; ++ks)
      af[ks] = *(const bf16x8*)(qB + ((size_t)(ii * 16 + c)) * D_ + h * HD_ + ks * 32 + quad * 8);
    __builtin_amdgcn_s_setprio(1);
    #pragma unroll
    for (int j = 0; j < 13; ++j) {
      f32x4 a = {};
      #pragma unroll
      for (int ks = 0; ks < 3; ++ks) {
        bf16x8 bf = *(const bf16x8*)&Ks[(j * 16 + c) * HD_ + ks * 32 + quad * 8];
        a = __builtin_amdgcn_mfma_f32_16x16x32_bf16(af[ks], bf, a, 0, 0, 0);
      }
      p[rep][j] = a;
    }
    __builtin_amdgcn_s_setprio(0);
    float m[4] = {-1e30f, -1e30f, -1e30f, -1e30f};
    #pragma unroll
    for (int j = 0; j < 13; ++j)
      #pragma unroll
      for (int r = 0; r < 4; ++r) {
        float v = p[rep][j][r] * scale;
        if (j == 12 && c >= 4) v = -1e30f;   // mask padded s 196..207 (kills NaN too)
        p[rep][j][r] = v;
        m[r] = fmaxf(m[r], v);
      }
    #pragma unroll
    for (int r = 0; r < 4; ++r) {
      m[r] = fmaxf(m[r], __shfl_xor(m[r], 1));
      m[r] = fmaxf(m[r], __shfl_xor(m[r], 2));
      m[r] = fmaxf(m[r], __shfl_xor(m[r], 4));
      m[r] = fmaxf(m[r], __shfl_xor(m[r], 8));
    }
    float lsum[4] = {0.f, 0.f, 0.f, 0.f};
    #pragma unroll
    for (int j = 0; j < 13; ++j)
      #pragma unroll
      for (int r = 0; r < 4; ++r) {
        float e = __expf(p[rep][j][r] - m[r]);
        p[rep][j][r] = e; lsum[r] += e;
      }
    #pragma unroll
    for (int r = 0; r < 4; ++r) {
      lsum[r] += __shfl_xor(lsum[r], 1);
      lsum[r] += __shfl_xor(lsum[r], 2);
      lsum[r] += __shfl_xor(lsum[r], 4);
      lsum[r] += __shfl_xor(lsum[r], 8);
      lsum[r] = 1.f / lsum[r];
    }
    #pragma unroll
    for (int j = 0; j < 13; ++j)
      #pragma unroll
      for (int r = 0; r < 4; ++r)
        p[rep][j][r] *= lsum[r];
  }
  __syncthreads();   // everyone done reading Ks -> safe to overwrite with Ps
  #pragma unroll
  for (int rep = 0; rep < 2; ++rep) {
    const int ii = wave + rep * 4;
    if (ii >= 7) continue;
    #pragma unroll
    for (int r = 0; r < 4; ++r) {
      const int g = ii * 16 + quad * 4 + r;
      #pragma unroll
      for (int j = 0; j < 13; ++j)
        Ps[g * SP_ + j * 16 + c] = f2bf(p[rep][j][r]);
      Ps[g * SP_ + 208 + c] = 0;   // pad s 208..223
    }
  }
  __syncthreads();
  #pragma unroll
  for (int rep = 0; rep < 2; ++rep) {
    const int ii = wave + rep * 4;
    if (ii >= 7) continue;
    bf16x8 af[7];
    #pragma unroll
    for (int k = 0; k < 7; ++k)
      af[k] = *(const bf16x8*)&Ps[(ii * 16 + c) * SP_ + k * 32 + quad * 8];
    #pragma unroll
    for (int j = 0; j < 6; ++j) {
      f32x4 acc = {};
      __builtin_amdgcn_s_setprio(1);
      #pragma unroll
      for (int k = 0; k < 7; ++k) {
        bf16x8 bf = *(const bf16x8*)(VbT + ((size_t)bh * HD_ + j * 16 + c) * SP_ + k * 32 + quad * 8);
        acc = __builtin_amdgcn_mfma_f32_16x16x32_bf16(af[k], bf, acc, 0, 0, 0);
      }
      __builtin_amdgcn_s_setprio(0);
      #pragma unroll
      for (int r = 0; r < 4; ++r) {
        const int g = ii * 16 + quad * 4 + r;
        if (g < G_)
          ctx[((size_t)(b * G_ + g)) * D_ + h * HD_ + j * 16 + c] = f2bf(acc[r]);
      }
    }
  }
}

// ---------------- residual + LayerNorm (add-input bf16) --------------------
// transb: bf16 out written transposed as [g][b][768] (for the head's A-operand)
__global__ __launch_bounds__(256) void k_lnres(const float* __restrict__ resid, int resid_mod,
    const ushort* __restrict__ addB, const float* __restrict__ gamma, const float* __restrict__ beta,
    float* __restrict__ outf, ushort* __restrict__ outb, int transb) {
  const int row = blockIdx.x, t = threadIdx.x;
  __shared__ float r1[256], r2[256];
  const float* rrow = resid + (size_t)(resid_mod ? (row % G_) : row) * D_;
  const ushort* arow = addB + (size_t)row * D_;
  float y[3]; float s = 0.f, sq = 0.f;
  #pragma unroll
  for (int i = 0; i < 3; ++i) {
    int d = t + i * 256;
    float v = rrow[d] + bf2f(arow[d]);
    y[i] = v; s += v; sq += v * v;
  }
  r1[t] = s; r2[t] = sq; __syncthreads();
  for (int o = 128; o > 0; o >>= 1) { if (t < o) { r1[t] += r1[t + o]; r2[t] += r2[t + o]; } __syncthreads(); }
  const float mean = r1[0] * (1.f / D_);
  const float var  = r2[0] * (1.f / D_) - mean * mean;
  const float w = rsqrtf(var + 1e-5f);
  const size_t orow = transb ? ((size_t)(row % G_) * B_ + row / G_) : (size_t)row;
  #pragma unroll
  for (int i = 0; i < 3; ++i) {
    int d = t + i * 256;
    float v = (y[i] - mean) * w * gamma[d] + beta[d];
    if (outf) outf[(size_t)row * D_ + d] = v;
    if (outb) outb[orow * D_ + d] = f2bf(v);
  }
}

// ---------------- grouped head via MFMA, LDS-free, coalesced ---------------
__global__ __launch_bounds__(256) void k_head4(const ushort* __restrict__ hT,
    const ushort* __restrict__ dupT, const float* __restrict__ dup_bias, float* __restrict__ out) {
  const int g = blockIdx.x, j = blockIdx.y, t = threadIdx.x;
  const int lane = t & 63, wave = t >> 6;
  const int quad = lane >> 4, c = lane & 15;
  const ushort* ap = hT + ((size_t)g * B_ + wave * 16 + c) * D_;
  const ushort* bp = dupT + ((size_t)g * FP_ + j * 16 + c) * D_;
  f32x4 acc = {};
  #pragma unroll 8
  for (int k0 = 0; k0 < D_; k0 += 32) {
    bf16x8 af = *(const bf16x8*)(ap + k0 + quad * 8);
    bf16x8 bf = *(const bf16x8*)(bp + k0 + quad * 8);
    acc = __builtin_amdgcn_mfma_f32_16x16x32_bf16(af, bf, acc, 0, 0, 0);
  }
  const int f = j * 16 + c;
  if (f >= DF_) return;
  const int n = g * DF_ + f;
  if (n >= NC_) return;
  const float bv = dup_bias[n];
  #pragma unroll
  for (int r = 0; r < 4; ++r) {
    const int b = wave * 16 + quad * 4 + r;
    out[(size_t)b * NC_ + n] = acc[r] + bv;
  }
}

// ---------------------------------------------------------------------------
// workspace layout (bytes)
// ---------------------------------------------------------------------------
static constexpr size_t OFF_VBT   = 0;          // bf16 [512,96,224]  = 22,020,096
static constexpr size_t OFF_FF    = 0;          // bf16 [6400,2048] = 26,214,400
static constexpr size_t OFF_FFO   = 26214400;   // bf16 [6400,768]  = 9,830,400 (end 36,044,800)
static constexpr size_t OFF_WEMB  = 51380224;   // bf16 3,145,728
static constexpr size_t OFF_MEM   = 54525952;   // bf16 [12544,768] = 19,267,584
static constexpr size_t OFF_WK    = 73793536;   // 1,179,648   (wk|wv contiguous = fused 1536x768)
static constexpr size_t OFF_WV    = 74973184;   // 1,179,648
static constexpr size_t OFF_WO    = 76152832;   // 1,179,648
static constexpr size_t OFF_W1    = 77332480;   // 3,145,728
static constexpr size_t OFF_W2    = 80478208;   // 3,145,728
static constexpr size_t OFF_DUP   = 83623936;   // bf16 [100,112,768] = 17,203,200
static constexpr size_t OFF_KB    = 100827136;  // bf16 [12544,768] = 19,267,584
static constexpr size_t OFF_TGT   = 139362304;  // f32 [100,768] = 307,200
static constexpr size_t OFF_TGTB  = 139669504;  // bf16 [128,768] = 196,608
static constexpr size_t OFF_Q     = 139866112;  // bf16 [128,768] = 196,608
static constexpr size_t OFF_CTX   = 140068864;  // bf16 9,830,400 (also wqB early: dead before attn)
static constexpr size_t OFF_WQ    = OFF_CTX;    // bf16 [768,768] = 1,179,648 (consumed before ctx written)
static constexpr size_t OFF_CTXO  = 149899264;  // bf16 [6400,768] = 9,830,400
static constexpr size_t OFF_TGT2F = 169560064;  // f32 19,660,800
static constexpr size_t OFF_TGT2B = 189220864;  // bf16 9,830,400
static constexpr size_t OFF_HB    = 199051264;  // bf16 [100,64,768] = 9,830,400 (end 208,881,664)

extern "C" void kernel_launch(void* const* d_in, const int* in_sizes, int n_in,
                              void* d_out, int out_size, void* d_ws, size_t ws_size,
                              hipStream_t stream) {
  const float* x           = (const float*)d_in[0];
  const float* w_embed     = (const float*)d_in[1];
  const float* b_embed     = (const float*)d_in[2];
  const float* query_embed = (const float*)d_in[3];
  const float* wq          = (const float*)d_in[4];
  const float* bq          = (const float*)d_in[5];
  const float* wk          = (const float*)d_in[6];
  const float* bk          = (const float*)d_in[7];
  const float* wv          = (const float*)d_in[8];
  const float* bv          = (const float*)d_in[9];
  const float* wo          = (const float*)d_in[10];
  const float* bo          = (const float*)d_in[11];
  const float* g1          = (const float*)d_in[12];
  const float* be1         = (const float*)d_in[13];
  const float* g2          = (const float*)d_in[14];
  const float* be2         = (const float*)d_in[15];
  const float* g3          = (const float*)d_in[16];
  const float* be3         = (const float*)d_in[17];
  const float* w1          = (const float*)d_in[18];
  const float* bl1         = (const float*)d_in[19];
  const float* w2          = (const float*)d_in[20];
  const float* bl2         = (const float*)d_in[21];
  const float* dup_pool    = (const float*)d_in[22];
  const float* dup_bias    = (const float*)d_in[23];
  float* out = (float*)d_out;
  char* ws = (char*)d_ws;

  ushort* wembB = (ushort*)(ws + OFF_WEMB);
  ushort* memB  = (ushort*)(ws + OFF_MEM);
  ushort* wkvB  = (ushort*)(ws + OFF_WK);    // fused [1536][768]
  ushort* wkB   = (ushort*)(ws + OFF_WK);
  ushort* wvB   = (ushort*)(ws + OFF_WV);
  ushort* woB   = (ushort*)(ws + OFF_WO);
  ushort* w1B   = (ushort*)(ws + OFF_W1);
  ushort* w2B   = (ushort*)(ws + OFF_W2);
  ushort* wqB   = (ushort*)(ws + OFF_WQ);
  ushort* dupT  = (ushort*)(ws + OFF_DUP);
  ushort* Kb    = (ushort*)(ws + OFF_KB);
  float*  tgtF  = (float*)(ws + OFF_TGT);
  ushort* tgtB  = (ushort*)(ws + OFF_TGTB);
  ushort* qB    = (ushort*)(ws + OFF_Q);
  ushort* VbT   = (ushort*)(ws + OFF_VBT);
  ushort* ctxB  = (ushort*)(ws + OFF_CTX);
  ushort* ctxoB = (ushort*)(ws + OFF_CTXO);
  float*  tgt2F = (float*)(ws + OFF_TGT2F);
  ushort* tgt2B = (ushort*)(ws + OFF_TGT2B);
  ushort* ffB   = (ushort*)(ws + OFF_FF);
  ushort* ffoB  = (ushort*)(ws + OFF_FFO);
  ushort* hT    = (ushort*)(ws + OFF_HB);

  // 1. prep (tiny): wemb/wq cvt + tgt LN
  PrepArgs pa;
  pa.csrc[0] = w_embed; pa.cdst[0] = wembB; pa.cn4[0] = D_ * CIN_ / 8;
  pa.csrc[1] = wq;      pa.cdst[1] = wqB;   pa.cn4[1] = D_ * D_ / 8;
  pa.ctotal = pa.cn4[0] + pa.cn4[1];
  pa.qe = query_embed; pa.g1 = g1; pa.be1 = be1; pa.tgt = tgtF; pa.tgtB = tgtB;
  k_prep<<<CVP_BLKS + TG_BLKS, 256, 0, stream>>>(pa);

  // 2. embed dispatch: dupT + embed GEMM (A straight from x, +relu) + q-proj
  //    + wk/wv/wo/w1/w2 cvt
  EmbArgs ea;
  ea.x = x; ea.wembB = wembB; ea.b_embed = b_embed; ea.memB = memB;
  ea.tgtB = tgtB; ea.wqB = wqB; ea.bq = bq; ea.qB = qB;
  ea.dup = dup_pool; ea.dupT = dupT;
  ea.csrc[0] = wk; ea.cdst[0] = wkB; ea.cn4[0] = D_ * D_ / 8;
  ea.csrc[1] = wv; ea.cdst[1] = wvB; ea.cn4[1] = D_ * D_ / 8;
  ea.csrc[2] = wo; ea.cdst[2] = woB; ea.cn4[2] = D_ * D_ / 8;
  ea.csrc[3] = w1; ea.cdst[3] = w1B; ea.cn4[3] = FF_ * D_ / 8;
  ea.csrc[4] = w2; ea.cdst[4] = w2B; ea.cn4[4] = D_ * FF_ / 8;
  ea.ctotal = ea.cn4[0] + ea.cn4[1] + ea.cn4[2] + ea.cn4[3] + ea.cn4[4];
  k_embed<<<DT2_BLKS + EG_BLKS + QP_BLKS + CV2_BLKS, 256, 0, stream>>>(ea);

  // 3. fused K|V projection: K -> Kb [12544,768], V -> VbT [512][96][224] transposed
  k_gemm<<<swz_grid(98, 12), 256, 0, stream>>>(memB, wkvB, bk, bv, nullptr, Kb, VbT,
                                               D_, D_, 12, 98, 0);

  // 4. fused attention (QK^T + softmax + PV)
  k_attn<<<dim3(NH_, B_), 256, 0, stream>>>(qB, Kb, VbT, ctxB);

  // 5. ctx @ wo^T + bo -> bf16 [6400, 768] (64-row tiles)
  k_gemm64<<<swz_grid(100, 6), 256, 0, stream>>>(ctxB, woB, bo, ctxoB, D_, D_, 6, 100, 0);

  // 6. tgt2 = LN(tgt + ctxo)
  k_lnres<<<BG_, 256, 0, stream>>>(tgtF, 1, ctxoB, g2, be2, tgt2F, tgt2B, 0);

  // 7-8. FFN
  k_gemm<<<swz_grid(50, 16), 256, 0, stream>>>(tgt2B, w1B, bl1, nullptr, nullptr, ffB, nullptr,
                                               FF_, D_, 16, 50, 1);
  k_gemm64<<<swz_grid(100, 6), 256, 0, stream>>>(ffB, w2B, bl2, ffoB, D_, FF_, 6, 100, 0);

  // 9. h = LN(tgt2 + ffo) -> bf16 transposed [g][64][768]
  k_lnres<<<BG_, 256, 0, stream>>>(tgt2F, 0, ffoB, g3, be3, nullptr, hT, 1);

  // 10. grouped head -> logits fp32 [64, 9605] via MFMA (coalesced, LDS-free)
  k_head4<<<dim3(G_, 7), 256, 0, stream>>>(hT, dupT, dup_bias, out);
}

// Round 8
// 566.991 us; speedup vs baseline: 1.0567x; 1.0194x over previous
//
#include <hip/hip_runtime.h>
#include <hip/hip_bf16.h>

// ---------------------------------------------------------------------------
// MLDecoder classification head, MI355X bf16-MFMA implementation.
// B=64, C_IN=2048, H=W=14 (S=196), D=768, FF=2048, G=100, NC=9605, NH=8, HD=96
// ---------------------------------------------------------------------------

#define B_    64
#define CIN_  2048
#define S_    196
#define D_    768
#define FF_   2048
#define G_    100
#define NC_   9605
#define NH_   8
#define HD_   96
#define DF_   97
#define FP_   112          // DF_ padded to 16
#define GP_   112          // G padded to 16
#define SP_   224          // S padded to 32 (7 K-steps) for P / V^T
#define BS_   (B_ * S_)   // 12544
#define BG_   (B_ * G_)   // 6400

typedef __bf16 bf16x8 __attribute__((ext_vector_type(8)));
typedef float  f32x4  __attribute__((ext_vector_type(4)));
typedef ushort us8    __attribute__((ext_vector_type(8)));

__device__ __forceinline__ float bf2f(ushort u) {
  union { unsigned int i; float f; } v; v.i = ((unsigned int)u) << 16; return v.f;
}
__device__ __forceinline__ ushort f2bf(float f) {
  __hip_bfloat16 h = __float2bfloat16(f);
  return *reinterpret_cast<ushort*>(&h);
}

// async global->LDS, 16 bytes per lane. LDS target must be wave-uniform base
// + lane*16 (our staging layouts satisfy this: lds byte offset == 16*i, i linear in t).
__device__ __forceinline__ void gl2lds16(const ushort* g, ushort* l) {
  __builtin_amdgcn_global_load_lds((const __attribute__((address_space(1))) unsigned int*)g,
                                   (__attribute__((address_space(3))) unsigned int*)l, 16, 0, 0);
}

// ---------------------------------------------------------------------------
// k_prep (R15 = R5 base): x-transpose + cvt(wemb,wq,wk,wv) + tgt LN.
// R15: wk/wv cvt moved here (needed by KV dispatch; prep has BW slack).
// xpose c-chunk 32: LDS 15.7 KB, ~10 blocks/CU.
// ---------------------------------------------------------------------------
#define XP_BLKS  4096   // xpose: (b, c-chunk of 32), full s
#define CVP_BLKS 256    // cvt: wemb+wq+wk+wv, grid-stride, 8-float units
#define TG_BLKS  128    // tgt LN rows (padded)

struct PrepArgs {
  const float* x;   ushort* aemb;
  const float* csrc[4]; ushort* cdst[4]; int cn4[4]; int ctotal;  // 8-float units
  const float* qe; const float* g1; const float* be1;
  float* tgt; ushort* tgtB;
};

__global__ __launch_bounds__(256) void k_prep(PrepArgs pa) {
  __shared__ __align__(16) char smem[196 * 40 * 2];   // 15,680 B
  int jid = blockIdx.x;
  const int t = threadIdx.x;

  if (jid < XP_BLKS) {
    // x [B][C][S] f32 -> aemb [(b,s)][C] bf16. Per block: one b, 32 c, all s.
    // LDS tile [196 s][40 c] bf16 (row 80 B, 16B-aligned). Phase 1: wave =
    // 8 j x 8 cq -> 8 rows x 128 B coalesced reads; ushort4 LDS writes ~2-way.
    // Phase 2: us8 reads + 64 B contiguous global stores (4 lanes/row).
    ushort* xs = (ushort*)smem;
    const int b = jid >> 6, cbase = (jid & 63) * 32;
    const float* xb = pa.x + ((size_t)b * CIN_ + cbase) * S_;
    #pragma unroll
    for (int it = 0; it < 2; ++it) {
      const int u = it * 256 + t;
      if (u < 392) {                       // 49 s-quads x 8 c-quads
        const int j = u >> 3, cq = u & 7;
        const int s = 4 * j;
        float4 a[4];
        #pragma unroll
        for (int r = 0; r < 4; ++r)
          a[r] = *(const float4*)(xb + (size_t)(cq * 4 + r) * S_ + s);
        #pragma unroll
        for (int r = 0; r < 4; ++r) {
          ushort4 o;
          o.x = f2bf(((const float*)&a[0])[r]);
          o.y = f2bf(((const float*)&a[1])[r]);
          o.z = f2bf(((const float*)&a[2])[r]);
          o.w = f2bf(((const float*)&a[3])[r]);
          *(ushort4*)&xs[(s + r) * 40 + cq * 4] = o;
        }
      }
    }
    __syncthreads();
    const int sl = t >> 2, oct = t & 3;    // 4 lanes -> 64 B contiguous store
    #pragma unroll
    for (int sr = 0; sr < 4; ++sr) {
      const int s = sr * 64 + sl;
      if (s < S_) {
        us8 v = *(const us8*)&xs[s * 40 + oct * 8];
        *(us8*)&pa.aemb[((size_t)(b * S_ + s)) * CIN_ + cbase + oct * 8] = v;
      }
    }
    return;
  }
  jid -= XP_BLKS;

  if (jid < CVP_BLKS) {
    // wemb + wq + wk + wv fp32 -> bf16, 8 floats per unit.
    int i = jid * 256 + t;
    const int stride = CVP_BLKS * 256;
    for (; i < pa.ctotal; i += stride) {
      int seg = 0, off = i;
      while (off >= pa.cn4[seg]) { off -= pa.cn4[seg]; ++seg; }
      const float4* sp = (const float4*)pa.csrc[seg];
      float4 v0 = sp[2 * off], v1 = sp[2 * off + 1];
      us8 o;
      o[0] = f2bf(v0.x); o[1] = f2bf(v0.y); o[2] = f2bf(v0.z); o[3] = f2bf(v0.w);
      o[4] = f2bf(v1.x); o[5] = f2bf(v1.y); o[6] = f2bf(v1.z); o[7] = f2bf(v1.w);
      ((us8*)pa.cdst[seg])[off] = o;
    }
    return;
  }
  jid -= CVP_BLKS;

  // tgt = LN(2*query_embed)*g1 + be1 -> fp32 [100,768] + bf16 [128,768] (pad 0)
  float* r1 = (float*)smem;
  float* r2 = r1 + 256;
  const int g = jid;
  if (g >= G_) {
    for (int d = t; d < D_; d += 256) pa.tgtB[(size_t)g * D_ + d] = 0;
    return;
  }
  float y[3]; float s = 0.f, sq = 0.f;
  const float* row = pa.qe + (size_t)g * D_;
  #pragma unroll
  for (int i = 0; i < 3; ++i) { float v = 2.f * row[t + i * 256]; y[i] = v; s += v; sq += v * v; }
  r1[t] = s; r2[t] = sq; __syncthreads();
  for (int o = 128; o > 0; o >>= 1) { if (t < o) { r1[t] += r1[t + o]; r2[t] += r2[t + o]; } __syncthreads(); }
  const float mean = r1[0] * (1.f / D_);
  const float var  = r2[0] * (1.f / D_) - mean * mean;
  const float w = rsqrtf(var + 1e-5f);
  #pragma unroll
  for (int i = 0; i < 3; ++i) {
    int d = t + i * 256;
    float v = (y[i] - mean) * w * pa.g1[d] + pa.be1[d];
    pa.tgt[(size_t)g * D_ + d] = v;
    pa.tgtB[(size_t)g * D_ + d] = f2bf(v);
  }
}

// ---------------- bf16 MFMA GEMM core: C[M,N] = A[M,K]*B[N,K]^T + bias -----
// 128x128 tile, BK=32, counted-vmcnt two-barrier k-loop (R11).
// KV mode (Vt != null): cols >= 768 are the V projection, written TRANSPOSED
// into VbT [bh][hd][s].
__device__ __forceinline__ void gemm_core(const ushort* __restrict__ A, const ushort* __restrict__ B,
    const float* __restrict__ bias, const float* __restrict__ bias2,
    float* __restrict__ Cf, ushort* __restrict__ Cb, ushort* __restrict__ Vt,
    int N, int K, int m0, int n0, int relu, ushort* As, ushort* Bs) {
  const int t = threadIdx.x;
  const int lane = t & 63, wave = t >> 6;
  const int quad = lane >> 4, lrow = lane & 15;
  const int wr = (wave >> 1) * 64, wc = (wave & 1) * 64;
  const int srow = t >> 2, scol = (t & 3) * 8;
  const ushort* ag = A + (size_t)(m0 + srow) * K + scol;
  const ushort* bg = B + (size_t)(n0 + srow) * K + scol;
  ushort* asw = As + t * 8;   // linear dest: byte 16*t within buffer
  ushort* bsw = Bs + t * 8;
  f32x4 acc[4][4] = {};
  gl2lds16(ag,                  asw);
  gl2lds16(ag + (size_t)64 * K, asw + 64 * 32);
  gl2lds16(bg,                  bsw);
  gl2lds16(bg + (size_t)64 * K, bsw + 64 * 32);
  int cur = 0;
  for (int k0 = 0; k0 < K; k0 += 32) {
    if (k0 + 32 < K) {                      // prefetch next k-step into other buf
      const int nb = (cur ^ 1) * (128 * 32);
      gl2lds16(ag + k0 + 32,                  asw + nb);
      gl2lds16(ag + k0 + 32 + (size_t)64 * K, asw + nb + 64 * 32);
      gl2lds16(bg + k0 + 32,                  bsw + nb);
      gl2lds16(bg + k0 + 32 + (size_t)64 * K, bsw + nb + 64 * 32);
      asm volatile("s_waitcnt vmcnt(4)" ::: "memory");   // cur staged; prefetch flying
    } else {
      asm volatile("s_waitcnt vmcnt(0)" ::: "memory");
    }
    __builtin_amdgcn_s_barrier();
    __builtin_amdgcn_sched_barrier(0);
    const ushort* as = As + cur * (128 * 32);
    const ushort* bs = Bs + cur * (128 * 32);
    bf16x8 af[4], bfr[4];
    #pragma unroll
    for (int i = 0; i < 4; ++i) af[i] = *(const bf16x8*)&as[(wr + i * 16 + lrow) * 32 + quad * 8];
    #pragma unroll
    for (int j = 0; j < 4; ++j) bfr[j] = *(const bf16x8*)&bs[(wc + j * 16 + lrow) * 32 + quad * 8];
    __builtin_amdgcn_s_setprio(1);
    #pragma unroll
    for (int i = 0; i < 4; ++i)
      #pragma unroll
      for (int j = 0; j < 4; ++j)
        acc[i][j] = __builtin_amdgcn_mfma_f32_16x16x32_bf16(af[i], bfr[j], acc[i][j], 0, 0, 0);
    __builtin_amdgcn_s_setprio(0);
    __builtin_amdgcn_sched_barrier(0);
    __builtin_amdgcn_s_barrier();           // all done reading cur -> safe to overwrite
    __builtin_amdgcn_sched_barrier(0);
    cur ^= 1;
  }
  #pragma unroll
  for (int i = 0; i < 4; ++i) {
    #pragma unroll
    for (int j = 0; j < 4; ++j) {
      const int gcol = n0 + wc + j * 16 + lrow;
      const float bv = (bias2 && gcol >= D_) ? bias2[gcol - D_] : (bias ? bias[gcol] : 0.f);
      if (Vt && gcol >= D_) {
        const int dv = gcol - D_, hh = dv / HD_, hd = dv % HD_;
        const int row0 = m0 + wr + i * 16 + quad * 4;
        const int bb = row0 / S_, ss = row0 % S_;
        ushort4 o;
        o.x = f2bf(acc[i][j][0] + bv);
        o.y = f2bf(acc[i][j][1] + bv);
        o.z = f2bf(acc[i][j][2] + bv);
        o.w = f2bf(acc[i][j][3] + bv);
        *(ushort4*)&Vt[((size_t)(bb * NH_ + hh) * HD_ + hd) * SP_ + ss] = o;
      } else {
        #pragma unroll
        for (int r = 0; r < 4; ++r) {
          const int grow = m0 + wr + i * 16 + quad * 4 + r;
          float v = acc[i][j][r] + bv;
          if (relu) v = fmaxf(v, 0.f);
          if (Cf) Cf[(size_t)grow * N + gcol] = v;
          else    Cb[(size_t)grow * N + gcol] = f2bf(v);
        }
      }
    }
  }
}

// R15: optional dup-transpose TAIL job (l >= swizzle base): dupT isn't needed
// until k_head4, so its 400 small blocks fill this dispatch's drain instead
// of stealing CU slots at the front of the embed dispatch (R5's mistake).
__global__ __launch_bounds__(256) void k_gemm(const ushort* __restrict__ A, const ushort* __restrict__ B,
    const float* __restrict__ bias, const float* __restrict__ bias2,
    float* __restrict__ Cf, ushort* __restrict__ Cb, ushort* __restrict__ Vt,
    int N, int K, int nbx, int nm, int relu,
    const float* __restrict__ dup, ushort* __restrict__ dupTp) {
  __shared__ ushort As[2 * 128 * 32];
  __shared__ ushort Bs[2 * 128 * 32];
  const int l = blockIdx.x;
  const int base = ((nm + 7) & ~7) * nbx;
  if (l >= base) {
    // dup_pool [g][d][f=97] -> dupT [g][f=112][d] bf16, f zero-padded.
    float (*tile)[33] = (float (*)[33])As;   // 4356 B, fits
    const int jid = l - base;
    const int g = jid >> 2, dchunk = jid & 3;
    const int t = threadIdx.x;
    const int tx = t & 31, ty = t >> 5;
    for (int di = 0; di < 6; ++di) {
      const int d0 = dchunk * 192 + di * 32;
      for (int f0 = 0; f0 < 128; f0 += 32) {
        #pragma unroll
        for (int r = 0; r < 32; r += 8) {
          int d = d0 + ty + r, f = f0 + tx;
          tile[ty + r][tx] = (f < DF_) ? dup[(size_t)g * D_ * DF_ + (size_t)d * DF_ + f] : 0.f;
        }
        __syncthreads();
        #pragma unroll
        for (int r = 0; r < 32; r += 8) {
          int f = f0 + ty + r, d = d0 + tx;
          if (f < FP_) dupTp[((size_t)g * FP_ + f) * D_ + d] = f2bf(tile[tx][ty + r]);
        }
        __syncthreads();
      }
    }
    return;
  }
  const int mb = (l >> 3) / nbx * 8 + (l & 7);
  const int nb = (l >> 3) % nbx;
  if (mb >= nm) return;
  gemm_core(A, B, bias, bias2, Cf, Cb, Vt, N, K, mb * 128, nb * 128, relu, As, Bs);
}
static inline int swz_grid(int nm, int nbx) { return ((nm + 7) & ~7) * nbx; }

// ---------------- 64x128-tile GEMM core (R9/R11) ---------------------------
__device__ __forceinline__ void gemm_core64(const ushort* __restrict__ A, const ushort* __restrict__ B,
    const float* __restrict__ bias, ushort* __restrict__ Cb,
    int N, int K, int m0, int n0, int relu, ushort* As, ushort* Bs) {
  const int t = threadIdx.x;
  const int lane = t & 63, wave = t >> 6;
  const int quad = lane >> 4, lrow = lane & 15;
  const int wr = (wave >> 1) * 32, wc = (wave & 1) * 64;
  const int srow = t >> 2, scol = (t & 3) * 8;
  const ushort* ag = A + (size_t)(m0 + srow) * K + scol;
  const ushort* bg = B + (size_t)(n0 + srow) * K + scol;
  ushort* asw = As + t * 8;
  ushort* bsw = Bs + t * 8;
  f32x4 acc[2][4] = {};
  gl2lds16(ag,                  asw);
  gl2lds16(bg,                  bsw);
  gl2lds16(bg + (size_t)64 * K, bsw + 64 * 32);
  int cur = 0;
  for (int k0 = 0; k0 < K; k0 += 32) {
    if (k0 + 32 < K) {
      gl2lds16(ag + k0 + 32,                  asw + (cur ^ 1) * (64 * 32));
      gl2lds16(bg + k0 + 32,                  bsw + (cur ^ 1) * (128 * 32));
      gl2lds16(bg + k0 + 32 + (size_t)64 * K, bsw + (cur ^ 1) * (128 * 32) + 64 * 32);
      asm volatile("s_waitcnt vmcnt(3)" ::: "memory");
    } else {
      asm volatile("s_waitcnt vmcnt(0)" ::: "memory");
    }
    __builtin_amdgcn_s_barrier();
    __builtin_amdgcn_sched_barrier(0);
    const ushort* as = As + cur * (64 * 32);
    const ushort* bs = Bs + cur * (128 * 32);
    bf16x8 af[2], bfr[4];
    #pragma unroll
    for (int i = 0; i < 2; ++i) af[i] = *(const bf16x8*)&as[(wr + i * 16 + lrow) * 32 + quad * 8];
    #pragma unroll
    for (int j = 0; j < 4; ++j) bfr[j] = *(const bf16x8*)&bs[(wc + j * 16 + lrow) * 32 + quad * 8];
    __builtin_amdgcn_s_setprio(1);
    #pragma unroll
    for (int i = 0; i < 2; ++i)
      #pragma unroll
      for (int j = 0; j < 4; ++j)
        acc[i][j] = __builtin_amdgcn_mfma_f32_16x16x32_bf16(af[i], bfr[j], acc[i][j], 0, 0, 0);
    __builtin_amdgcn_s_setprio(0);
    __builtin_amdgcn_sched_barrier(0);
    __builtin_amdgcn_s_barrier();
    __builtin_amdgcn_sched_barrier(0);
    cur ^= 1;
  }
  #pragma unroll
  for (int i = 0; i < 2; ++i) {
    #pragma unroll
    for (int j = 0; j < 4; ++j) {
      const int gcol = n0 + wc + j * 16 + lrow;
      const float bv = bias ? bias[gcol] : 0.f;
      #pragma unroll
      for (int r = 0; r < 4; ++r) {
        const int grow = m0 + wr + i * 16 + quad * 4 + r;
        float v = acc[i][j][r] + bv;
        if (relu) v = fmaxf(v, 0.f);
        Cb[(size_t)grow * N + gcol] = f2bf(v);
      }
    }
  }
}

__global__ __launch_bounds__(256) void k_gemm64(const ushort* __restrict__ A, const ushort* __restrict__ B,
    const float* __restrict__ bias, ushort* __restrict__ Cb,
    int N, int K, int nbx, int nm, int relu) {
  __shared__ ushort As[2 * 64 * 32];
  __shared__ ushort Bs[2 * 128 * 32];
  const int l = blockIdx.x;
  const int mb = (l >> 3) / nbx * 8 + (l & 7);
  const int nb = (l >> 3) % nbx;
  if (mb >= nm) return;
  gemm_core64(A, B, bias, Cb, N, K, mb * 64, nb * 128, relu, As, Bs);
}

// ---------------- embed dispatch (R15): GEMM FIRST, then qproj, then cvt ---
// R5 put 400 dupT blocks at the front: they held CU slots before any GEMM
// block launched (embed 84 -> 108 us). Now the long GEMM jobs start first
// (LPT), and the short cvt blocks fill the drain. dupT moved to KV tail.
#define EG_BLKS  1200      // swz_grid(196, 6)
#define QP_BLKS  12
#define CV2_BLKS 256

struct EmbArgs {
  const ushort* aemb; const ushort* wembB; const float* b_embed; ushort* memB;
  const ushort* tgtB; const ushort* wqB;   const float* bq;      ushort* qB;
  const float* csrc[3]; ushort* cdst[3]; int cn4[3]; int ctotal;  // 8-float units
};

__global__ __launch_bounds__(256) void k_embed(EmbArgs ea) {
  __shared__ ushort As[2 * 64 * 32];
  __shared__ ushort Bs[2 * 128 * 32];
  int l = blockIdx.x;
  const int t = threadIdx.x;

  if (l < EG_BLKS) {
    const int mb = (l >> 3) / 6 * 8 + (l & 7);
    const int nb = (l >> 3) % 6;
    if (mb >= 196) return;
    gemm_core64(ea.aemb, ea.wembB, ea.b_embed, ea.memB, D_, CIN_, mb * 64, nb * 128, 1, As, Bs);
    return;
  }
  l -= EG_BLKS;

  if (l < QP_BLKS) {
    // qB[128][768] = tgtB @ wq^T + bq
    gemm_core64(ea.tgtB, ea.wqB, ea.bq, ea.qB, D_, D_, (l / 6) * 64, (l % 6) * 128, 0, As, Bs);
    return;
  }
  l -= QP_BLKS;

  // wo/w1/w2 fp32 -> bf16, grid-stride
  int i = l * 256 + t;
  const int stride = CV2_BLKS * 256;
  for (; i < ea.ctotal; i += stride) {
    int seg = 0, off = i;
    while (off >= ea.cn4[seg]) { off -= ea.cn4[seg]; ++seg; }
    const float4* sp = (const float4*)ea.csrc[seg];
    float4 v0 = sp[2 * off], v1 = sp[2 * off + 1];
    us8 o;
    o[0] = f2bf(v0.x); o[1] = f2bf(v0.y); o[2] = f2bf(v0.z); o[3] = f2bf(v0.w);
    o[4] = f2bf(v1.x); o[5] = f2bf(v1.y); o[6] = f2bf(v1.z); o[7] = f2bf(v1.w);
    ((us8*)ea.cdst[seg])[off] = o;
  }
}

// ---------------- fused attention: QK^T + softmax + PV ---------------------
__global__ __launch_bounds__(256) void k_attn(const ushort* __restrict__ qB,
    const ushort* __restrict__ Kb, const ushort* __restrict__ VbT, ushort* __restrict__ ctx) {
  __shared__ ushort lds[GP_ * SP_];   // 50176 B; first 39936 B doubles as K stage
  ushort* Ks = lds;
  ushort* Ps = lds;
  const int h = blockIdx.x, b = blockIdx.y, t = threadIdx.x;
  const int bh = b * NH_ + h;
  const int lane = t & 63, wave = t >> 6;
  const int quad = lane >> 4, c = lane & 15;
  for (int i = t; i < 208 * 12; i += 256) {
    int r = i / 12, col = (i % 12) * 8;
    gl2lds16(Kb + ((size_t)(b * S_ + r)) * D_ + h * HD_ + col, &Ks[i * 8]);
  }
  __syncthreads();
  const float scale = 0.1020620726f;  // 1/sqrt(96)
  f32x4 p[2][13];
  #pragma unroll
  for (int rep = 0; rep < 2; ++rep) {
    const int ii = wave + rep * 4;
    if (ii >= 7) continue;
    bf16x8 af[3];
    #pragma unroll
    for (int ks = 0; ks < 3; ++ks)
      af[ks] = *(const bf16x8*)(qB + ((size_t)(ii * 16 + c)) * D_ + h * HD_ + ks * 32 + quad * 8);
    __builtin_amdgcn_s_setprio(1);
    #pragma unroll
    for (int j = 0; j < 13; ++j) {
      f32x4 a = {};
      #pragma unroll
      for (int ks = 0; ks < 3; ++ks) {
        bf16x8 bf = *(const bf16x8*)&Ks[(j * 16 + c) * HD_ + ks * 32 + quad * 8];
        a = __builtin_amdgcn_mfma_f32_16x16x32_bf16(af[ks], bf, a, 0, 0, 0);
      }
      p[rep][j] = a;
    }
    __builtin_amdgcn_s_setprio(0);
    float m[4] = {-1e30f, -1e30f, -1e30f, -1e30f};
    #pragma unroll
    for (int j = 0; j < 13; ++j)
      #pragma unroll
      for (int r = 0; r < 4; ++r) {
        float v = p[rep][j][r] * scale;
        if (j == 12 && c >= 4) v = -1e30f;   // mask padded s 196..207 (kills NaN too)
        p[rep][j][r] = v;
        m[r] = fmaxf(m[r], v);
      }
    #pragma unroll
    for (int r = 0; r < 4; ++r) {
      m[r] = fmaxf(m[r], __shfl_xor(m[r], 1));
      m[r] = fmaxf(m[r], __shfl_xor(m[r], 2));
      m[r] = fmaxf(m[r], __shfl_xor(m[r], 4));
      m[r] = fmaxf(m[r], __shfl_xor(m[r], 8));
    }
    float lsum[4] = {0.f, 0.f, 0.f, 0.f};
    #pragma unroll
    for (int j = 0; j < 13; ++j)
      #pragma unroll
      for (int r = 0; r < 4; ++r) {
        float e = __expf(p[rep][j][r] - m[r]);
        p[rep][j][r] = e; lsum[r] += e;
      }
    #pragma unroll
    for (int r = 0; r < 4; ++r) {
      lsum[r] += __shfl_xor(lsum[r], 1);
      lsum[r] += __shfl_xor(lsum[r], 2);
      lsum[r] += __shfl_xor(lsum[r], 4);
      lsum[r] += __shfl_xor(lsum[r], 8);
      lsum[r] = 1.f / lsum[r];
    }
    #pragma unroll
    for (int j = 0; j < 13; ++j)
      #pragma unroll
      for (int r = 0; r < 4; ++r)
        p[rep][j][r] *= lsum[r];
  }
  __syncthreads();   // everyone done reading Ks -> safe to overwrite with Ps
  #pragma unroll
  for (int rep = 0; rep < 2; ++rep) {
    const int ii = wave + rep * 4;
    if (ii >= 7) continue;
    #pragma unroll
    for (int r = 0; r < 4; ++r) {
      const int g = ii * 16 + quad * 4 + r;
      #pragma unroll
      for (int j = 0; j < 13; ++j)
        Ps[g * SP_ + j * 16 + c] = f2bf(p[rep][j][r]);
      Ps[g * SP_ + 208 + c] = 0;   // pad s 208..223
    }
  }
  __syncthreads();
  #pragma unroll
  for (int rep = 0; rep < 2; ++rep) {
    const int ii = wave + rep * 4;
    if (ii >= 7) continue;
    bf16x8 af[7];
    #pragma unroll
    for (int k = 0; k < 7; ++k)
      af[k] = *(const bf16x8*)&Ps[(ii * 16 + c) * SP_ + k * 32 + quad * 8];
    #pragma unroll
    for (int j = 0; j < 6; ++j) {
      f32x4 acc = {};
      __builtin_amdgcn_s_setprio(1);
      #pragma unroll
      for (int k = 0; k < 7; ++k) {
        bf16x8 bf = *(const bf16x8*)(VbT + ((size_t)bh * HD_ + j * 16 + c) * SP_ + k * 32 + quad * 8);
        acc = __builtin_amdgcn_mfma_f32_16x16x32_bf16(af[k], bf, acc, 0, 0, 0);
      }
      __builtin_amdgcn_s_setprio(0);
      #pragma unroll
      for (int r = 0; r < 4; ++r) {
        const int g = ii * 16 + quad * 4 + r;
        if (g < G_)
          ctx[((size_t)(b * G_ + g)) * D_ + h * HD_ + j * 16 + c] = f2bf(acc[r]);
      }
    }
  }
}

// ---------------- residual + LayerNorm (add-input bf16) --------------------
// transb: bf16 out written transposed as [g][b][768] (for the head's A-operand)
__global__ __launch_bounds__(256) void k_lnres(const float* __restrict__ resid, int resid_mod,
    const ushort* __restrict__ addB, const float* __restrict__ gamma, const float* __restrict__ beta,
    float* __restrict__ outf, ushort* __restrict__ outb, int transb) {
  const int row = blockIdx.x, t = threadIdx.x;
  __shared__ float r1[256], r2[256];
  const float* rrow = resid + (size_t)(resid_mod ? (row % G_) : row) * D_;
  const ushort* arow = addB + (size_t)row * D_;
  float y[3]; float s = 0.f, sq = 0.f;
  #pragma unroll
  for (int i = 0; i < 3; ++i) {
    int d = t + i * 256;
    float v = rrow[d] + bf2f(arow[d]);
    y[i] = v; s += v; sq += v * v;
  }
  r1[t] = s; r2[t] = sq; __syncthreads();
  for (int o = 128; o > 0; o >>= 1) { if (t < o) { r1[t] += r1[t + o]; r2[t] += r2[t + o]; } __syncthreads(); }
  const float mean = r1[0] * (1.f / D_);
  const float var  = r2[0] * (1.f / D_) - mean * mean;
  const float w = rsqrtf(var + 1e-5f);
  const size_t orow = transb ? ((size_t)(row % G_) * B_ + row / G_) : (size_t)row;
  #pragma unroll
  for (int i = 0; i < 3; ++i) {
    int d = t + i * 256;
    float v = (y[i] - mean) * w * gamma[d] + beta[d];
    if (outf) outf[(size_t)row * D_ + d] = v;
    if (outb) outb[orow * D_ + d] = f2bf(v);
  }
}

// ---------------- grouped head via MFMA, LDS-free, coalesced ---------------
__global__ __launch_bounds__(256) void k_head4(const ushort* __restrict__ hT,
    const ushort* __restrict__ dupT, const float* __restrict__ dup_bias, float* __restrict__ out) {
  const int g = blockIdx.x, j = blockIdx.y, t = threadIdx.x;
  const int lane = t & 63, wave = t >> 6;
  const int quad = lane >> 4, c = lane & 15;
  const ushort* ap = hT + ((size_t)g * B_ + wave * 16 + c) * D_;
  const ushort* bp = dupT + ((size_t)g * FP_ + j * 16 + c) * D_;
  f32x4 acc = {};
  #pragma unroll 8
  for (int k0 = 0; k0 < D_; k0 += 32) {
    bf16x8 af = *(const bf16x8*)(ap + k0 + quad * 8);
    bf16x8 bf = *(const bf16x8*)(bp + k0 + quad * 8);
    acc = __builtin_amdgcn_mfma_f32_16x16x32_bf16(af, bf, acc, 0, 0, 0);
  }
  const int f = j * 16 + c;
  if (f >= DF_) return;
  const int n = g * DF_ + f;
  if (n >= NC_) return;
  const float bv = dup_bias[n];
  #pragma unroll
  for (int r = 0; r < 4; ++r) {
    const int b = wave * 16 + quad * 4 + r;
    out[(size_t)b * NC_ + n] = acc[r] + bv;
  }
}

// ---------------------------------------------------------------------------
// workspace layout (bytes)
// region 0 timeline: aemb (until embed GEMM) -> VbT (KV epilogue .. attn) ->
//                    ffB/ffoB (FFN)
// ---------------------------------------------------------------------------
static constexpr size_t OFF_AEMB  = 0;          // bf16 [12544,2048] = 51,380,224
static constexpr size_t OFF_VBT   = 0;          // bf16 [512,96,224]  = 22,020,096
static constexpr size_t OFF_FF    = 0;          // bf16 [6400,2048] = 26,214,400
static constexpr size_t OFF_FFO   = 26214400;   // bf16 [6400,768]  = 9,830,400 (end 36,044,800)
static constexpr size_t OFF_WEMB  = 51380224;   // bf16 3,145,728
static constexpr size_t OFF_MEM   = 54525952;   // bf16 [12544,768] = 19,267,584
static constexpr size_t OFF_WK    = 73793536;   // 1,179,648   (wk|wv contiguous = fused 1536x768)
static constexpr size_t OFF_WV    = 74973184;   // 1,179,648
static constexpr size_t OFF_WO    = 76152832;   // 1,179,648
static constexpr size_t OFF_W1    = 77332480;   // 3,145,728
static constexpr size_t OFF_W2    = 80478208;   // 3,145,728
static constexpr size_t OFF_DUP   = 83623936;   // bf16 [100,112,768] = 17,203,200
static constexpr size_t OFF_KB    = 100827136;  // bf16 [12544,768] = 19,267,584
static constexpr size_t OFF_TGT   = 139362304;  // f32 [100,768] = 307,200
static constexpr size_t OFF_TGTB  = 139669504;  // bf16 [128,768] = 196,608
static constexpr size_t OFF_Q     = 139866112;  // bf16 [128,768] = 196,608
static constexpr size_t OFF_CTX   = 140068864;  // bf16 9,830,400 (also wqB early: dead before attn)
static constexpr size_t OFF_WQ    = OFF_CTX;    // bf16 [768,768] = 1,179,648 (consumed before ctx written)
static constexpr size_t OFF_CTXO  = 149899264;  // bf16 [6400,768] = 9,830,400
static constexpr size_t OFF_TGT2F = 169560064;  // f32 19,660,800
static constexpr size_t OFF_TGT2B = 189220864;  // bf16 9,830,400
static constexpr size_t OFF_HB    = 199051264;  // bf16 [100,64,768] = 9,830,400 (end 208,881,664)

extern "C" void kernel_launch(void* const* d_in, const int* in_sizes, int n_in,
                              void* d_out, int out_size, void* d_ws, size_t ws_size,
                              hipStream_t stream) {
  const float* x           = (const float*)d_in[0];
  const float* w_embed     = (const float*)d_in[1];
  const float* b_embed     = (const float*)d_in[2];
  const float* query_embed = (const float*)d_in[3];
  const float* wq          = (const float*)d_in[4];
  const float* bq          = (const float*)d_in[5];
  const float* wk          = (const float*)d_in[6];
  const float* bk          = (const float*)d_in[7];
  const float* wv          = (const float*)d_in[8];
  const float* bv          = (const float*)d_in[9];
  const float* wo          = (const float*)d_in[10];
  const float* bo          = (const float*)d_in[11];
  const float* g1          = (const float*)d_in[12];
  const float* be1         = (const float*)d_in[13];
  const float* g2          = (const float*)d_in[14];
  const float* be2         = (const float*)d_in[15];
  const float* g3          = (const float*)d_in[16];
  const float* be3         = (const float*)d_in[17];
  const float* w1          = (const float*)d_in[18];
  const float* bl1         = (const float*)d_in[19];
  const float* w2          = (const float*)d_in[20];
  const float* bl2         = (const float*)d_in[21];
  const float* dup_pool    = (const float*)d_in[22];
  const float* dup_bias    = (const float*)d_in[23];
  float* out = (float*)d_out;
  char* ws = (char*)d_ws;

  ushort* aemb  = (ushort*)(ws + OFF_AEMB);
  ushort* wembB = (ushort*)(ws + OFF_WEMB);
  ushort* memB  = (ushort*)(ws + OFF_MEM);
  ushort* wkvB  = (ushort*)(ws + OFF_WK);    // fused [1536][768]
  ushort* wkB   = (ushort*)(ws + OFF_WK);
  ushort* wvB   = (ushort*)(ws + OFF_WV);
  ushort* woB   = (ushort*)(ws + OFF_WO);
  ushort* w1B   = (ushort*)(ws + OFF_W1);
  ushort* w2B   = (ushort*)(ws + OFF_W2);
  ushort* wqB   = (ushort*)(ws + OFF_WQ);
  ushort* dupT  = (ushort*)(ws + OFF_DUP);
  ushort* Kb    = (ushort*)(ws + OFF_KB);
  float*  tgtF  = (float*)(ws + OFF_TGT);
  ushort* tgtB  = (ushort*)(ws + OFF_TGTB);
  ushort* qB    = (ushort*)(ws + OFF_Q);
  ushort* VbT   = (ushort*)(ws + OFF_VBT);
  ushort* ctxB  = (ushort*)(ws + OFF_CTX);
  ushort* ctxoB = (ushort*)(ws + OFF_CTXO);
  float*  tgt2F = (float*)(ws + OFF_TGT2F);
  ushort* tgt2B = (ushort*)(ws + OFF_TGT2B);
  ushort* ffB   = (ushort*)(ws + OFF_FF);
  ushort* ffoB  = (ushort*)(ws + OFF_FFO);
  ushort* hT    = (ushort*)(ws + OFF_HB);

  // 1. prep: x-transpose + cvt(wemb,wq,wk,wv) + tgt LN
  PrepArgs pa;
  pa.x = x; pa.aemb = aemb;
  pa.csrc[0] = w_embed; pa.cdst[0] = wembB; pa.cn4[0] = D_ * CIN_ / 8;
  pa.csrc[1] = wq;      pa.cdst[1] = wqB;   pa.cn4[1] = D_ * D_ / 8;
  pa.csrc[2] = wk;      pa.cdst[2] = wkB;   pa.cn4[2] = D_ * D_ / 8;
  pa.csrc[3] = wv;      pa.cdst[3] = wvB;   pa.cn4[3] = D_ * D_ / 8;
  pa.ctotal = pa.cn4[0] + pa.cn4[1] + pa.cn4[2] + pa.cn4[3];
  pa.qe = query_embed; pa.g1 = g1; pa.be1 = be1; pa.tgt = tgtF; pa.tgtB = tgtB;
  k_prep<<<XP_BLKS + CVP_BLKS + TG_BLKS, 256, 0, stream>>>(pa);

  // 2. embed dispatch: embed GEMM (+relu) FIRST, then q-proj, then wo/w1/w2 cvt
  EmbArgs ea;
  ea.aemb = aemb; ea.wembB = wembB; ea.b_embed = b_embed; ea.memB = memB;
  ea.tgtB = tgtB; ea.wqB = wqB; ea.bq = bq; ea.qB = qB;
  ea.csrc[0] = wo; ea.cdst[0] = woB; ea.cn4[0] = D_ * D_ / 8;
  ea.csrc[1] = w1; ea.cdst[1] = w1B; ea.cn4[1] = FF_ * D_ / 8;
  ea.csrc[2] = w2; ea.cdst[2] = w2B; ea.cn4[2] = D_ * FF_ / 8;
  ea.ctotal = ea.cn4[0] + ea.cn4[1] + ea.cn4[2];
  k_embed<<<EG_BLKS + QP_BLKS + CV2_BLKS, 256, 0, stream>>>(ea);

  // 3. fused K|V projection (+ dupT tail blocks: fills this dispatch's drain;
  //    dupT not needed until k_head4)
  k_gemm<<<swz_grid(98, 12) + 400, 256, 0, stream>>>(memB, wkvB, bk, bv, nullptr, Kb, VbT,
                                                     D_, D_, 12, 98, 0, dup_pool, dupT);

  // 4. fused attention (QK^T + softmax + PV)
  k_attn<<<dim3(NH_, B_), 256, 0, stream>>>(qB, Kb, VbT, ctxB);

  // 5. ctx @ wo^T + bo -> bf16 [6400, 768] (64-row tiles)
  k_gemm64<<<swz_grid(100, 6), 256, 0, stream>>>(ctxB, woB, bo, ctxoB, D_, D_, 6, 100, 0);

  // 6. tgt2 = LN(tgt + ctxo)
  k_lnres<<<BG_, 256, 0, stream>>>(tgtF, 1, ctxoB, g2, be2, tgt2F, tgt2B, 0);

  // 7-8. FFN
  k_gemm<<<swz_grid(50, 16), 256, 0, stream>>>(tgt2B, w1B, bl1, nullptr, nullptr, ffB, nullptr,
                                               FF_, D_, 16, 50, 1, nullptr, nullptr);
  k_gemm64<<<swz_grid(100, 6), 256, 0, stream>>>(ffB, w2B, bl2, ffoB, D_, FF_, 6, 100, 0);

  // 9. h = LN(tgt2 + ffo) -> bf16 transposed [g][64][768]
  k_lnres<<<BG_, 256, 0, stream>>>(tgt2F, 0, ffoB, g3, be3, nullptr, hT, 1);

  // 10. grouped head -> logits fp32 [64, 9605] via MFMA (coalesced, LDS-free)
  k_head4<<<dim3(G_, 7), 256, 0, stream>>>(hT, dupT, dup_bias, out);
}

// Round 10
// 559.340 us; speedup vs baseline: 1.0711x; 1.0137x over previous
//
#include <hip/hip_runtime.h>
#include <hip/hip_bf16.h>

// ---------------------------------------------------------------------------
// MLDecoder classification head, MI355X bf16-MFMA implementation.
// B=64, C_IN=2048, H=W=14 (S=196), D=768, FF=2048, G=100, NC=9605, NH=8, HD=96
// R17: revert R16's cooperative tail (launch silently failed -> zero output).
// Structure = R15 with dupT moved from KV-tail (+14us there) to the embed
// dispatch tail (deepest-drain dispatch: K=2048, 64 k-steps per GEMM block).
// ---------------------------------------------------------------------------

#define B_    64
#define CIN_  2048
#define S_    196
#define D_    768
#define FF_   2048
#define G_    100
#define NC_   9605
#define NH_   8
#define HD_   96
#define DF_   97
#define FP_   112          // DF_ padded to 16
#define GP_   112          // G padded to 16
#define SP_   224          // S padded to 32 (7 K-steps) for P / V^T
#define BS_   (B_ * S_)   // 12544
#define BG_   (B_ * G_)   // 6400

typedef __bf16 bf16x8 __attribute__((ext_vector_type(8)));
typedef float  f32x4  __attribute__((ext_vector_type(4)));
typedef ushort us8    __attribute__((ext_vector_type(8)));

__device__ __forceinline__ float bf2f(ushort u) {
  union { unsigned int i; float f; } v; v.i = ((unsigned int)u) << 16; return v.f;
}
__device__ __forceinline__ ushort f2bf(float f) {
  __hip_bfloat16 h = __float2bfloat16(f);
  return *reinterpret_cast<ushort*>(&h);
}

// async global->LDS, 16 bytes per lane. LDS target must be wave-uniform base
// + lane*16 (our staging layouts satisfy this: lds byte offset == 16*i, i linear in t).
__device__ __forceinline__ void gl2lds16(const ushort* g, ushort* l) {
  __builtin_amdgcn_global_load_lds((const __attribute__((address_space(1))) unsigned int*)g,
                                   (__attribute__((address_space(3))) unsigned int*)l, 16, 0, 0);
}

// ---------------------------------------------------------------------------
// k_prep: x-transpose + cvt(wemb,wq,wk,wv) + tgt LN.
// ---------------------------------------------------------------------------
#define XP_BLKS  4096   // xpose: (b, c-chunk of 32), full s
#define CVP_BLKS 256    // cvt: wemb+wq+wk+wv, grid-stride, 8-float units
#define TG_BLKS  128    // tgt LN rows (padded)

struct PrepArgs {
  const float* x;   ushort* aemb;
  const float* csrc[4]; ushort* cdst[4]; int cn4[4]; int ctotal;  // 8-float units
  const float* qe; const float* g1; const float* be1;
  float* tgt; ushort* tgtB;
};

__global__ __launch_bounds__(256) void k_prep(PrepArgs pa) {
  __shared__ __align__(16) char smem[196 * 40 * 2];   // 15,680 B
  int jid = blockIdx.x;
  const int t = threadIdx.x;

  if (jid < XP_BLKS) {
    // x [B][C][S] f32 -> aemb [(b,s)][C] bf16. Per block: one b, 32 c, all s.
    ushort* xs = (ushort*)smem;
    const int b = jid >> 6, cbase = (jid & 63) * 32;
    const float* xb = pa.x + ((size_t)b * CIN_ + cbase) * S_;
    #pragma unroll
    for (int it = 0; it < 2; ++it) {
      const int u = it * 256 + t;
      if (u < 392) {                       // 49 s-quads x 8 c-quads
        const int j = u >> 3, cq = u & 7;
        const int s = 4 * j;
        float4 a[4];
        #pragma unroll
        for (int r = 0; r < 4; ++r)
          a[r] = *(const float4*)(xb + (size_t)(cq * 4 + r) * S_ + s);
        #pragma unroll
        for (int r = 0; r < 4; ++r) {
          ushort4 o;
          o.x = f2bf(((const float*)&a[0])[r]);
          o.y = f2bf(((const float*)&a[1])[r]);
          o.z = f2bf(((const float*)&a[2])[r]);
          o.w = f2bf(((const float*)&a[3])[r]);
          *(ushort4*)&xs[(s + r) * 40 + cq * 4] = o;
        }
      }
    }
    __syncthreads();
    const int sl = t >> 2, oct = t & 3;    // 4 lanes -> 64 B contiguous store
    #pragma unroll
    for (int sr = 0; sr < 4; ++sr) {
      const int s = sr * 64 + sl;
      if (s < S_) {
        us8 v = *(const us8*)&xs[s * 40 + oct * 8];
        *(us8*)&pa.aemb[((size_t)(b * S_ + s)) * CIN_ + cbase + oct * 8] = v;
      }
    }
    return;
  }
  jid -= XP_BLKS;

  if (jid < CVP_BLKS) {
    int i = jid * 256 + t;
    const int stride = CVP_BLKS * 256;
    for (; i < pa.ctotal; i += stride) {
      int seg = 0, off = i;
      while (off >= pa.cn4[seg]) { off -= pa.cn4[seg]; ++seg; }
      const float4* sp = (const float4*)pa.csrc[seg];
      float4 v0 = sp[2 * off], v1 = sp[2 * off + 1];
      us8 o;
      o[0] = f2bf(v0.x); o[1] = f2bf(v0.y); o[2] = f2bf(v0.z); o[3] = f2bf(v0.w);
      o[4] = f2bf(v1.x); o[5] = f2bf(v1.y); o[6] = f2bf(v1.z); o[7] = f2bf(v1.w);
      ((us8*)pa.cdst[seg])[off] = o;
    }
    return;
  }
  jid -= CVP_BLKS;

  // tgt = LN(2*query_embed)*g1 + be1 -> fp32 [100,768] + bf16 [128,768] (pad 0)
  float* r1 = (float*)smem;
  float* r2 = r1 + 256;
  const int g = jid;
  if (g >= G_) {
    for (int d = t; d < D_; d += 256) pa.tgtB[(size_t)g * D_ + d] = 0;
    return;
  }
  float y[3]; float s = 0.f, sq = 0.f;
  const float* row = pa.qe + (size_t)g * D_;
  #pragma unroll
  for (int i = 0; i < 3; ++i) { float v = 2.f * row[t + i * 256]; y[i] = v; s += v; sq += v * v; }
  r1[t] = s; r2[t] = sq; __syncthreads();
  for (int o = 128; o > 0; o >>= 1) { if (t < o) { r1[t] += r1[t + o]; r2[t] += r2[t + o]; } __syncthreads(); }
  const float mean = r1[0] * (1.f / D_);
  const float var  = r2[0] * (1.f / D_) - mean * mean;
  const float w = rsqrtf(var + 1e-5f);
  #pragma unroll
  for (int i = 0; i < 3; ++i) {
    int d = t + i * 256;
    float v = (y[i] - mean) * w * pa.g1[d] + pa.be1[d];
    pa.tgt[(size_t)g * D_ + d] = v;
    pa.tgtB[(size_t)g * D_ + d] = f2bf(v);
  }
}

// ---------------- bf16 MFMA GEMM core: C[M,N] = A[M,K]*B[N,K]^T + bias -----
// 128x128 tile, BK=32, counted-vmcnt two-barrier k-loop (R11).
// KV mode (Vt != null): cols >= 768 are the V projection, written TRANSPOSED
// into VbT [bh][hd][s].
__device__ __forceinline__ void gemm_core(const ushort* __restrict__ A, const ushort* __restrict__ B,
    const float* __restrict__ bias, const float* __restrict__ bias2,
    float* __restrict__ Cf, ushort* __restrict__ Cb, ushort* __restrict__ Vt,
    int N, int K, int m0, int n0, int relu, ushort* As, ushort* Bs) {
  const int t = threadIdx.x;
  const int lane = t & 63, wave = t >> 6;
  const int quad = lane >> 4, lrow = lane & 15;
  const int wr = (wave >> 1) * 64, wc = (wave & 1) * 64;
  const int srow = t >> 2, scol = (t & 3) * 8;
  const ushort* ag = A + (size_t)(m0 + srow) * K + scol;
  const ushort* bg = B + (size_t)(n0 + srow) * K + scol;
  ushort* asw = As + t * 8;   // linear dest: byte 16*t within buffer
  ushort* bsw = Bs + t * 8;
  f32x4 acc[4][4] = {};
  gl2lds16(ag,                  asw);
  gl2lds16(ag + (size_t)64 * K, asw + 64 * 32);
  gl2lds16(bg,                  bsw);
  gl2lds16(bg + (size_t)64 * K, bsw + 64 * 32);
  int cur = 0;
  for (int k0 = 0; k0 < K; k0 += 32) {
    if (k0 + 32 < K) {                      // prefetch next k-step into other buf
      const int nb = (cur ^ 1) * (128 * 32);
      gl2lds16(ag + k0 + 32,                  asw + nb);
      gl2lds16(ag + k0 + 32 + (size_t)64 * K, asw + nb + 64 * 32);
      gl2lds16(bg + k0 + 32,                  bsw + nb);
      gl2lds16(bg + k0 + 32 + (size_t)64 * K, bsw + nb + 64 * 32);
      asm volatile("s_waitcnt vmcnt(4)" ::: "memory");   // cur staged; prefetch flying
    } else {
      asm volatile("s_waitcnt vmcnt(0)" ::: "memory");
    }
    __builtin_amdgcn_s_barrier();
    __builtin_amdgcn_sched_barrier(0);
    const ushort* as = As + cur * (128 * 32);
    const ushort* bs = Bs + cur * (128 * 32);
    bf16x8 af[4], bfr[4];
    #pragma unroll
    for (int i = 0; i < 4; ++i) af[i] = *(const bf16x8*)&as[(wr + i * 16 + lrow) * 32 + quad * 8];
    #pragma unroll
    for (int j = 0; j < 4; ++j) bfr[j] = *(const bf16x8*)&bs[(wc + j * 16 + lrow) * 32 + quad * 8];
    __builtin_amdgcn_s_setprio(1);
    #pragma unroll
    for (int i = 0; i < 4; ++i)
      #pragma unroll
      for (int j = 0; j < 4; ++j)
        acc[i][j] = __builtin_amdgcn_mfma_f32_16x16x32_bf16(af[i], bfr[j], acc[i][j], 0, 0, 0);
    __builtin_amdgcn_s_setprio(0);
    __builtin_amdgcn_sched_barrier(0);
    __builtin_amdgcn_s_barrier();           // all done reading cur -> safe to overwrite
    __builtin_amdgcn_sched_barrier(0);
    cur ^= 1;
  }
  #pragma unroll
  for (int i = 0; i < 4; ++i) {
    #pragma unroll
    for (int j = 0; j < 4; ++j) {
      const int gcol = n0 + wc + j * 16 + lrow;
      const float bv = (bias2 && gcol >= D_) ? bias2[gcol - D_] : (bias ? bias[gcol] : 0.f);
      if (Vt && gcol >= D_) {
        const int dv = gcol - D_, hh = dv / HD_, hd = dv % HD_;
        const int row0 = m0 + wr + i * 16 + quad * 4;
        const int bb = row0 / S_, ss = row0 % S_;
        ushort4 o;
        o.x = f2bf(acc[i][j][0] + bv);
        o.y = f2bf(acc[i][j][1] + bv);
        o.z = f2bf(acc[i][j][2] + bv);
        o.w = f2bf(acc[i][j][3] + bv);
        *(ushort4*)&Vt[((size_t)(bb * NH_ + hh) * HD_ + hd) * SP_ + ss] = o;
      } else {
        #pragma unroll
        for (int r = 0; r < 4; ++r) {
          const int grow = m0 + wr + i * 16 + quad * 4 + r;
          float v = acc[i][j][r] + bv;
          if (relu) v = fmaxf(v, 0.f);
          if (Cf) Cf[(size_t)grow * N + gcol] = v;
          else    Cb[(size_t)grow * N + gcol] = f2bf(v);
        }
      }
    }
  }
}

__global__ __launch_bounds__(256) void k_gemm(const ushort* __restrict__ A, const ushort* __restrict__ B,
    const float* __restrict__ bias, const float* __restrict__ bias2,
    float* __restrict__ Cf, ushort* __restrict__ Cb, ushort* __restrict__ Vt,
    int N, int K, int nbx, int nm, int relu) {
  __shared__ ushort As[2 * 128 * 32];
  __shared__ ushort Bs[2 * 128 * 32];
  const int l = blockIdx.x;
  const int mb = (l >> 3) / nbx * 8 + (l & 7);
  const int nb = (l >> 3) % nbx;
  if (mb >= nm) return;
  gemm_core(A, B, bias, bias2, Cf, Cb, Vt, N, K, mb * 128, nb * 128, relu, As, Bs);
}
static inline int swz_grid(int nm, int nbx) { return ((nm + 7) & ~7) * nbx; }

// ---------------- 64x128-tile GEMM core (R9/R11) ---------------------------
__device__ __forceinline__ void gemm_core64(const ushort* __restrict__ A, const ushort* __restrict__ B,
    const float* __restrict__ bias, ushort* __restrict__ Cb,
    int N, int K, int m0, int n0, int relu, ushort* As, ushort* Bs) {
  const int t = threadIdx.x;
  const int lane = t & 63, wave = t >> 6;
  const int quad = lane >> 4, lrow = lane & 15;
  const int wr = (wave >> 1) * 32, wc = (wave & 1) * 64;
  const int srow = t >> 2, scol = (t & 3) * 8;
  const ushort* ag = A + (size_t)(m0 + srow) * K + scol;
  const ushort* bg = B + (size_t)(n0 + srow) * K + scol;
  ushort* asw = As + t * 8;
  ushort* bsw = Bs + t * 8;
  f32x4 acc[2][4] = {};
  gl2lds16(ag,                  asw);
  gl2lds16(bg,                  bsw);
  gl2lds16(bg + (size_t)64 * K, bsw + 64 * 32);
  int cur = 0;
  for (int k0 = 0; k0 < K; k0 += 32) {
    if (k0 + 32 < K) {
      gl2lds16(ag + k0 + 32,                  asw + (cur ^ 1) * (64 * 32));
      gl2lds16(bg + k0 + 32,                  bsw + (cur ^ 1) * (128 * 32));
      gl2lds16(bg + k0 + 32 + (size_t)64 * K, bsw + (cur ^ 1) * (128 * 32) + 64 * 32);
      asm volatile("s_waitcnt vmcnt(3)" ::: "memory");
    } else {
      asm volatile("s_waitcnt vmcnt(0)" ::: "memory");
    }
    __builtin_amdgcn_s_barrier();
    __builtin_amdgcn_sched_barrier(0);
    const ushort* as = As + cur * (64 * 32);
    const ushort* bs = Bs + cur * (128 * 32);
    bf16x8 af[2], bfr[4];
    #pragma unroll
    for (int i = 0; i < 2; ++i) af[i] = *(const bf16x8*)&as[(wr + i * 16 + lrow) * 32 + quad * 8];
    #pragma unroll
    for (int j = 0; j < 4; ++j) bfr[j] = *(const bf16x8*)&bs[(wc + j * 16 + lrow) * 32 + quad * 8];
    __builtin_amdgcn_s_setprio(1);
    #pragma unroll
    for (int i = 0; i < 2; ++i)
      #pragma unroll
      for (int j = 0; j < 4; ++j)
        acc[i][j] = __builtin_amdgcn_mfma_f32_16x16x32_bf16(af[i], bfr[j], acc[i][j], 0, 0, 0);
    __builtin_amdgcn_s_setprio(0);
    __builtin_amdgcn_sched_barrier(0);
    __builtin_amdgcn_s_barrier();
    __builtin_amdgcn_sched_barrier(0);
    cur ^= 1;
  }
  #pragma unroll
  for (int i = 0; i < 2; ++i) {
    #pragma unroll
    for (int j = 0; j < 4; ++j) {
      const int gcol = n0 + wc + j * 16 + lrow;
      const float bv = bias ? bias[gcol] : 0.f;
      #pragma unroll
      for (int r = 0; r < 4; ++r) {
        const int grow = m0 + wr + i * 16 + quad * 4 + r;
        float v = acc[i][j][r] + bv;
        if (relu) v = fmaxf(v, 0.f);
        Cb[(size_t)grow * N + gcol] = f2bf(v);
      }
    }
  }
}

__global__ __launch_bounds__(256) void k_gemm64(const ushort* __restrict__ A, const ushort* __restrict__ B,
    const float* __restrict__ bias, ushort* __restrict__ Cb,
    int N, int K, int nbx, int nm, int relu) {
  __shared__ ushort As[2 * 64 * 32];
  __shared__ ushort Bs[2 * 128 * 32];
  const int l = blockIdx.x;
  const int mb = (l >> 3) / nbx * 8 + (l & 7);
  const int nb = (l >> 3) % nbx;
  if (mb >= nm) return;
  gemm_core64(A, B, bias, Cb, N, K, mb * 64, nb * 128, relu, As, Bs);
}

// ---------------- embed dispatch (R17): GEMM -> qproj -> dupT -> cvt -------
// Embed GEMM blocks are the deepest in the pipeline (K=2048, 64 k-steps) so
// this dispatch has the longest drain window; the 400 dupT blocks + 256 cvt
// blocks backfill it. dupT is only needed by k_head4 (last dispatch).
#define EG_BLKS  1200      // swz_grid(196, 6)
#define QP_BLKS  12
#define DT2_BLKS 400
#define CV2_BLKS 256

struct EmbArgs {
  const ushort* aemb; const ushort* wembB; const float* b_embed; ushort* memB;
  const ushort* tgtB; const ushort* wqB;   const float* bq;      ushort* qB;
  const float* dup; ushort* dupT;
  const float* csrc[3]; ushort* cdst[3]; int cn4[3]; int ctotal;  // 8-float units
};

__global__ __launch_bounds__(256) void k_embed(EmbArgs ea) {
  __shared__ ushort As[2 * 64 * 32];
  __shared__ ushort Bs[2 * 128 * 32];
  int l = blockIdx.x;
  const int t = threadIdx.x;

  if (l < EG_BLKS) {
    const int mb = (l >> 3) / 6 * 8 + (l & 7);
    const int nb = (l >> 3) % 6;
    if (mb >= 196) return;
    gemm_core64(ea.aemb, ea.wembB, ea.b_embed, ea.memB, D_, CIN_, mb * 64, nb * 128, 1, As, Bs);
    return;
  }
  l -= EG_BLKS;

  if (l < QP_BLKS) {
    gemm_core64(ea.tgtB, ea.wqB, ea.bq, ea.qB, D_, D_, (l / 6) * 64, (l % 6) * 128, 0, As, Bs);
    return;
  }
  l -= QP_BLKS;

  if (l < DT2_BLKS) {
    // dup_pool [g][d][f=97] -> dupT [g][f=112][d] bf16, f zero-padded.
    float (*tile)[33] = (float (*)[33])As;   // 4356 B, fits in As
    const int g = l >> 2, dchunk = l & 3;
    const int tx = t & 31, ty = t >> 5;
    for (int di = 0; di < 6; ++di) {
      const int d0 = dchunk * 192 + di * 32;
      for (int f0 = 0; f0 < 128; f0 += 32) {
        #pragma unroll
        for (int r = 0; r < 32; r += 8) {
          int d = d0 + ty + r, f = f0 + tx;
          tile[ty + r][tx] = (f < DF_) ? ea.dup[(size_t)g * D_ * DF_ + (size_t)d * DF_ + f] : 0.f;
        }
        __syncthreads();
        #pragma unroll
        for (int r = 0; r < 32; r += 8) {
          int f = f0 + ty + r, d = d0 + tx;
          if (f < FP_) ea.dupT[((size_t)g * FP_ + f) * D_ + d] = f2bf(tile[tx][ty + r]);
        }
        __syncthreads();
      }
    }
    return;
  }
  l -= DT2_BLKS;

  int i = l * 256 + t;
  const int stride = CV2_BLKS * 256;
  for (; i < ea.ctotal; i += stride) {
    int seg = 0, off = i;
    while (off >= ea.cn4[seg]) { off -= ea.cn4[seg]; ++seg; }
    const float4* sp = (const float4*)ea.csrc[seg];
    float4 v0 = sp[2 * off], v1 = sp[2 * off + 1];
    us8 o;
    o[0] = f2bf(v0.x); o[1] = f2bf(v0.y); o[2] = f2bf(v0.z); o[3] = f2bf(v0.w);
    o[4] = f2bf(v1.x); o[5] = f2bf(v1.y); o[6] = f2bf(v1.z); o[7] = f2bf(v1.w);
    ((us8*)ea.cdst[seg])[off] = o;
  }
}

// ---------------- fused attention: QK^T + softmax + PV ---------------------
__global__ __launch_bounds__(256) void k_attn(const ushort* __restrict__ qB,
    const ushort* __restrict__ Kb, const ushort* __restrict__ VbT, ushort* __restrict__ ctx) {
  __shared__ ushort lds[GP_ * SP_];   // 50176 B; first 39936 B doubles as K stage
  ushort* Ks = lds;
  ushort* Ps = lds;
  const int h = blockIdx.x, b = blockIdx.y, t = threadIdx.x;
  const int bh = b * NH_ + h;
  const int lane = t & 63, wave = t >> 6;
  const int quad = lane >> 4, c = lane & 15;
  for (int i = t; i < 208 * 12; i += 256) {
    int r = i / 12, col = (i % 12) * 8;
    gl2lds16(Kb + ((size_t)(b * S_ + r)) * D_ + h * HD_ + col, &Ks[i * 8]);
  }
  __syncthreads();
  const float scale = 0.1020620726f;  // 1/sqrt(96)
  f32x4 p[2][13];
  #pragma unroll
  for (int rep = 0; rep < 2; ++rep) {
    const int ii = wave + rep * 4;
    if (ii >= 7) continue;
    bf16x8 af[3];
    #pragma unroll
    for (int ks = 0; ks < 3; ++ks)
      af[ks] = *(const bf16x8*)(qB + ((size_t)(ii * 16 + c)) * D_ + h * HD_ + ks * 32 + quad * 8);
    __builtin_amdgcn_s_setprio(1);
    #pragma unroll
    for (int j = 0; j < 13; ++j) {
      f32x4 a = {};
      #pragma unroll
      for (int ks = 0; ks < 3; ++ks) {
        bf16x8 bf = *(const bf16x8*)&Ks[(j * 16 + c) * HD_ + ks * 32 + quad * 8];
        a = __builtin_amdgcn_mfma_f32_16x16x32_bf16(af[ks], bf, a, 0, 0, 0);
      }
      p[rep][j] = a;
    }
    __builtin_amdgcn_s_setprio(0);
    float m[4] = {-1e30f, -1e30f, -1e30f, -1e30f};
    #pragma unroll
    for (int j = 0; j < 13; ++j)
      #pragma unroll
      for (int r = 0; r < 4; ++r) {
        float v = p[rep][j][r] * scale;
        if (j == 12 && c >= 4) v = -1e30f;   // mask padded s 196..207 (kills NaN too)
        p[rep][j][r] = v;
        m[r] = fmaxf(m[r], v);
      }
    #pragma unroll
    for (int r = 0; r < 4; ++r) {
      m[r] = fmaxf(m[r], __shfl_xor(m[r], 1));
      m[r] = fmaxf(m[r], __shfl_xor(m[r], 2));
      m[r] = fmaxf(m[r], __shfl_xor(m[r], 4));
      m[r] = fmaxf(m[r], __shfl_xor(m[r], 8));
    }
    float lsum[4] = {0.f, 0.f, 0.f, 0.f};
    #pragma unroll
    for (int j = 0; j < 13; ++j)
      #pragma unroll
      for (int r = 0; r < 4; ++r) {
        float e = __expf(p[rep][j][r] - m[r]);
        p[rep][j][r] = e; lsum[r] += e;
      }
    #pragma unroll
    for (int r = 0; r < 4; ++r) {
      lsum[r] += __shfl_xor(lsum[r], 1);
      lsum[r] += __shfl_xor(lsum[r], 2);
      lsum[r] += __shfl_xor(lsum[r], 4);
      lsum[r] += __shfl_xor(lsum[r], 8);
      lsum[r] = 1.f / lsum[r];
    }
    #pragma unroll
    for (int j = 0; j < 13; ++j)
      #pragma unroll
      for (int r = 0; r < 4; ++r)
        p[rep][j][r] *= lsum[r];
  }
  __syncthreads();   // everyone done reading Ks -> safe to overwrite with Ps
  #pragma unroll
  for (int rep = 0; rep < 2; ++rep) {
    const int ii = wave + rep * 4;
    if (ii >= 7) continue;
    #pragma unroll
    for (int r = 0; r < 4; ++r) {
      const int g = ii * 16 + quad * 4 + r;
      #pragma unroll
      for (int j = 0; j < 13; ++j)
        Ps[g * SP_ + j * 16 + c] = f2bf(p[rep][j][r]);
      Ps[g * SP_ + 208 + c] = 0;   // pad s 208..223
    }
  }
  __syncthreads();
  #pragma unroll
  for (int rep = 0; rep < 2; ++rep) {
    const int ii = wave + rep * 4;
    if (ii >= 7) continue;
    bf16x8 af[7];
    #pragma unroll
    for (int k = 0; k < 7; ++k)
      af[k] = *(const bf16x8*)&Ps[(ii * 16 + c) * SP_ + k * 32 + quad * 8];
    #pragma unroll
    for (int j = 0; j < 6; ++j) {
      f32x4 acc = {};
      __builtin_amdgcn_s_setprio(1);
      #pragma unroll
      for (int k = 0; k < 7; ++k) {
        bf16x8 bf = *(const bf16x8*)(VbT + ((size_t)bh * HD_ + j * 16 + c) * SP_ + k * 32 + quad * 8);
        acc = __builtin_amdgcn_mfma_f32_16x16x32_bf16(af[k], bf, acc, 0, 0, 0);
      }
      __builtin_amdgcn_s_setprio(0);
      #pragma unroll
      for (int r = 0; r < 4; ++r) {
        const int g = ii * 16 + quad * 4 + r;
        if (g < G_)
          ctx[((size_t)(b * G_ + g)) * D_ + h * HD_ + j * 16 + c] = f2bf(acc[r]);
      }
    }
  }
}

// ---------------- residual + LayerNorm (add-input bf16) --------------------
// transb: bf16 out written transposed as [g][b][768] (for the head's A-operand)
__global__ __launch_bounds__(256) void k_lnres(const float* __restrict__ resid, int resid_mod,
    const ushort* __restrict__ addB, const float* __restrict__ gamma, const float* __restrict__ beta,
    float* __restrict__ outf, ushort* __restrict__ outb, int transb) {
  const int row = blockIdx.x, t = threadIdx.x;
  __shared__ float r1[256], r2[256];
  const float* rrow = resid + (size_t)(resid_mod ? (row % G_) : row) * D_;
  const ushort* arow = addB + (size_t)row * D_;
  float y[3]; float s = 0.f, sq = 0.f;
  #pragma unroll
  for (int i = 0; i < 3; ++i) {
    int d = t + i * 256;
    float v = rrow[d] + bf2f(arow[d]);
    y[i] = v; s += v; sq += v * v;
  }
  r1[t] = s; r2[t] = sq; __syncthreads();
  for (int o = 128; o > 0; o >>= 1) { if (t < o) { r1[t] += r1[t + o]; r2[t] += r2[t + o]; } __syncthreads(); }
  const float mean = r1[0] * (1.f / D_);
  const float var  = r2[0] * (1.f / D_) - mean * mean;
  const float w = rsqrtf(var + 1e-5f);
  const size_t orow = transb ? ((size_t)(row % G_) * B_ + row / G_) : (size_t)row;
  #pragma unroll
  for (int i = 0; i < 3; ++i) {
    int d = t + i * 256;
    float v = (y[i] - mean) * w * gamma[d] + beta[d];
    if (outf) outf[(size_t)row * D_ + d] = v;
    if (outb) outb[orow * D_ + d] = f2bf(v);
  }
}

// ---------------- grouped head via MFMA, LDS-free, coalesced ---------------
__global__ __launch_bounds__(256) void k_head4(const ushort* __restrict__ hT,
    const ushort* __restrict__ dupT, const float* __restrict__ dup_bias, float* __restrict__ out) {
  const int g = blockIdx.x, j = blockIdx.y, t = threadIdx.x;
  const int lane = t & 63, wave = t >> 6;
  const int quad = lane >> 4, c = lane & 15;
  const ushort* ap = hT + ((size_t)g * B_ + wave * 16 + c) * D_;
  const ushort* bp = dupT + ((size_t)g * FP_ + j * 16 + c) * D_;
  f32x4 acc = {};
  #pragma unroll 8
  for (int k0 = 0; k0 < D_; k0 += 32) {
    bf16x8 af = *(const bf16x8*)(ap + k0 + quad * 8);
    bf16x8 bf = *(const bf16x8*)(bp + k0 + quad * 8);
    acc = __builtin_amdgcn_mfma_f32_16x16x32_bf16(af, bf, acc, 0, 0, 0);
  }
  const int f = j * 16 + c;
  if (f >= DF_) return;
  const int n = g * DF_ + f;
  if (n >= NC_) return;
  const float bv = dup_bias[n];
  #pragma unroll
  for (int r = 0; r < 4; ++r) {
    const int b = wave * 16 + quad * 4 + r;
    out[(size_t)b * NC_ + n] = acc[r] + bv;
  }
}

// ---------------------------------------------------------------------------
// workspace layout (bytes)
// region 0 timeline: aemb (until embed GEMM) -> VbT (KV epilogue .. attn) ->
//                    ffB/ffoB (FFN)
// ---------------------------------------------------------------------------
static constexpr size_t OFF_AEMB  = 0;          // bf16 [12544,2048] = 51,380,224
static constexpr size_t OFF_VBT   = 0;          // bf16 [512,96,224]  = 22,020,096
static constexpr size_t OFF_FF    = 0;          // bf16 [6400,2048] = 26,214,400
static constexpr size_t OFF_FFO   = 26214400;   // bf16 [6400,768]  = 9,830,400 (end 36,044,800)
static constexpr size_t OFF_WEMB  = 51380224;   // bf16 3,145,728
static constexpr size_t OFF_MEM   = 54525952;   // bf16 [12544,768] = 19,267,584
static constexpr size_t OFF_WK    = 73793536;   // 1,179,648   (wk|wv contiguous = fused 1536x768)
static constexpr size_t OFF_WV    = 74973184;   // 1,179,648
static constexpr size_t OFF_WO    = 76152832;   // 1,179,648
static constexpr size_t OFF_W1    = 77332480;   // 3,145,728
static constexpr size_t OFF_W2    = 80478208;   // 3,145,728
static constexpr size_t OFF_DUP   = 83623936;   // bf16 [100,112,768] = 17,203,200
static constexpr size_t OFF_KB    = 100827136;  // bf16 [12544,768] = 19,267,584
static constexpr size_t OFF_TGT   = 139362304;  // f32 [100,768] = 307,200
static constexpr size_t OFF_TGTB  = 139669504;  // bf16 [128,768] = 196,608
static constexpr size_t OFF_Q     = 139866112;  // bf16 [128,768] = 196,608
static constexpr size_t OFF_CTX   = 140068864;  // bf16 9,830,400 (also wqB early: dead before attn)
static constexpr size_t OFF_WQ    = OFF_CTX;    // bf16 [768,768] = 1,179,648 (consumed before ctx written)
static constexpr size_t OFF_CTXO  = 149899264;  // bf16 [6400,768] = 9,830,400
static constexpr size_t OFF_TGT2F = 169560064;  // f32 19,660,800
static constexpr size_t OFF_TGT2B = 189220864;  // bf16 9,830,400
static constexpr size_t OFF_HB    = 199051264;  // bf16 [100,64,768] = 9,830,400 (end 208,881,664)

extern "C" void kernel_launch(void* const* d_in, const int* in_sizes, int n_in,
                              void* d_out, int out_size, void* d_ws, size_t ws_size,
                              hipStream_t stream) {
  const float* x           = (const float*)d_in[0];
  const float* w_embed     = (const float*)d_in[1];
  const float* b_embed     = (const float*)d_in[2];
  const float* query_embed = (const float*)d_in[3];
  const float* wq          = (const float*)d_in[4];
  const float* bq          = (const float*)d_in[5];
  const float* wk          = (const float*)d_in[6];
  const float* bk          = (const float*)d_in[7];
  const float* wv          = (const float*)d_in[8];
  const float* bv          = (const float*)d_in[9];
  const float* wo          = (const float*)d_in[10];
  const float* bo          = (const float*)d_in[11];
  const float* g1          = (const float*)d_in[12];
  const float* be1         = (const float*)d_in[13];
  const float* g2          = (const float*)d_in[14];
  const float* be2         = (const float*)d_in[15];
  const float* g3          = (const float*)d_in[16];
  const float* be3         = (const float*)d_in[17];
  const float* w1          = (const float*)d_in[18];
  const float* bl1         = (const float*)d_in[19];
  const float* w2          = (const float*)d_in[20];
  const float* bl2         = (const float*)d_in[21];
  const float* dup_pool    = (const float*)d_in[22];
  const float* dup_bias    = (const float*)d_in[23];
  float* out = (float*)d_out;
  char* ws = (char*)d_ws;

  ushort* aemb  = (ushort*)(ws + OFF_AEMB);
  ushort* wembB = (ushort*)(ws + OFF_WEMB);
  ushort* memB  = (ushort*)(ws + OFF_MEM);
  ushort* wkvB  = (ushort*)(ws + OFF_WK);    // fused [1536][768]
  ushort* wkB   = (ushort*)(ws + OFF_WK);
  ushort* wvB   = (ushort*)(ws + OFF_WV);
  ushort* woB   = (ushort*)(ws + OFF_WO);
  ushort* w1B   = (ushort*)(ws + OFF_W1);
  ushort* w2B   = (ushort*)(ws + OFF_W2);
  ushort* wqB   = (ushort*)(ws + OFF_WQ);
  ushort* dupT  = (ushort*)(ws + OFF_DUP);
  ushort* Kb    = (ushort*)(ws + OFF_KB);
  float*  tgtF  = (float*)(ws + OFF_TGT);
  ushort* tgtB  = (ushort*)(ws + OFF_TGTB);
  ushort* qB    = (ushort*)(ws + OFF_Q);
  ushort* VbT   = (ushort*)(ws + OFF_VBT);
  ushort* ctxB  = (ushort*)(ws + OFF_CTX);
  ushort* ctxoB = (ushort*)(ws + OFF_CTXO);
  float*  tgt2F = (float*)(ws + OFF_TGT2F);
  ushort* tgt2B = (ushort*)(ws + OFF_TGT2B);
  ushort* ffB   = (ushort*)(ws + OFF_FF);
  ushort* ffoB  = (ushort*)(ws + OFF_FFO);
  ushort* hT    = (ushort*)(ws + OFF_HB);

  // 1. prep: x-transpose + cvt(wemb,wq,wk,wv) + tgt LN
  PrepArgs pa;
  pa.x = x; pa.aemb = aemb;
  pa.csrc[0] = w_embed; pa.cdst[0] = wembB; pa.cn4[0] = D_ * CIN_ / 8;
  pa.csrc[1] = wq;      pa.cdst[1] = wqB;   pa.cn4[1] = D_ * D_ / 8;
  pa.csrc[2] = wk;      pa.cdst[2] = wkB;   pa.cn4[2] = D_ * D_ / 8;
  pa.csrc[3] = wv;      pa.cdst[3] = wvB;   pa.cn4[3] = D_ * D_ / 8;
  pa.ctotal = pa.cn4[0] + pa.cn4[1] + pa.cn4[2] + pa.cn4[3];
  pa.qe = query_embed; pa.g1 = g1; pa.be1 = be1; pa.tgt = tgtF; pa.tgtB = tgtB;
  k_prep<<<XP_BLKS + CVP_BLKS + TG_BLKS, 256, 0, stream>>>(pa);

  // 2. embed dispatch: embed GEMM (+relu) -> q-proj -> dupT -> wo/w1/w2 cvt
  EmbArgs ea;
  ea.aemb = aemb; ea.wembB = wembB; ea.b_embed = b_embed; ea.memB = memB;
  ea.tgtB = tgtB; ea.wqB = wqB; ea.bq = bq; ea.qB = qB;
  ea.dup = dup_pool; ea.dupT = dupT;
  ea.csrc[0] = wo; ea.cdst[0] = woB; ea.cn4[0] = D_ * D_ / 8;
  ea.csrc[1] = w1; ea.cdst[1] = w1B; ea.cn4[1] = FF_ * D_ / 8;
  ea.csrc[2] = w2; ea.cdst[2] = w2B; ea.cn4[2] = D_ * FF_ / 8;
  ea.ctotal = ea.cn4[0] + ea.cn4[1] + ea.cn4[2];
  k_embed<<<EG_BLKS + QP_BLKS + DT2_BLKS + CV2_BLKS, 256, 0, stream>>>(ea);

  // 3. fused K|V projection: K -> Kb, V -> VbT (transposed)
  k_gemm<<<swz_grid(98, 12), 256, 0, stream>>>(memB, wkvB, bk, bv, nullptr, Kb, VbT,
                                               D_, D_, 12, 98, 0);

  // 4. fused attention (QK^T + softmax + PV)
  k_attn<<<dim3(NH_, B_), 256, 0, stream>>>(qB, Kb, VbT, ctxB);

  // 5. ctx @ wo^T + bo -> bf16 [6400, 768] (64-row tiles)
  k_gemm64<<<swz_grid(100, 6), 256, 0, stream>>>(ctxB, woB, bo, ctxoB, D_, D_, 6, 100, 0);

  // 6. tgt2 = LN(tgt + ctxo)
  k_lnres<<<BG_, 256, 0, stream>>>(tgtF, 1, ctxoB, g2, be2, tgt2F, tgt2B, 0);

  // 7-8. FFN
  k_gemm<<<swz_grid(50, 16), 256, 0, stream>>>(tgt2B, w1B, bl1, nullptr, nullptr, ffB, nullptr,
                                               FF_, D_, 16, 50, 1);
  k_gemm64<<<swz_grid(100, 6), 256, 0, stream>>>(ffB, w2B, bl2, ffoB, D_, FF_, 6, 100, 0);

  // 9. h = LN(tgt2 + ffo) -> bf16 transposed [g][64][768]
  k_lnres<<<BG_, 256, 0, stream>>>(tgt2F, 0, ffoB, g3, be3, nullptr, hT, 1);

  // 10. grouped head -> logits fp32 [64, 9605] via MFMA (coalesced, LDS-free)
  k_head4<<<dim3(G_, 7), 256, 0, stream>>>(hT, dupT, dup_bias, out);
}

// Round 11
// 546.242 us; speedup vs baseline: 1.0968x; 1.0240x over previous
//
#include <hip/hip_runtime.h>
#include <hip/hip_bf16.h>

// ---------------------------------------------------------------------------
// MLDecoder classification head, MI355X bf16-MFMA implementation.
// B=64, C_IN=2048, H=W=14 (S=196), D=768, FF=2048, G=100, NC=9605, NH=8, HD=96
// R18: dupT pass DELETED — every placement of the 400-block transpose job
// cost ~20-25us (R5/R8/R15/R17 zero-sum). k_head4 now stages dup_pool
// directly into an XOR-swizzled LDS tile (transpose-on-stage), saving the
// job + 34 MB of dupT write/re-read traffic. Embed = verified R15 form.
// ---------------------------------------------------------------------------

#define B_    64
#define CIN_  2048
#define S_    196
#define D_    768
#define FF_   2048
#define G_    100
#define NC_   9605
#define NH_   8
#define HD_   96
#define DF_   97
#define FP_   112          // DF_ padded to 16
#define GP_   112          // G padded to 16
#define SP_   224          // S padded to 32 (7 K-steps) for P / V^T
#define BS_   (B_ * S_)   // 12544
#define BG_   (B_ * G_)   // 6400

typedef __bf16 bf16x8 __attribute__((ext_vector_type(8)));
typedef float  f32x4  __attribute__((ext_vector_type(4)));
typedef ushort us8    __attribute__((ext_vector_type(8)));

__device__ __forceinline__ float bf2f(ushort u) {
  union { unsigned int i; float f; } v; v.i = ((unsigned int)u) << 16; return v.f;
}
__device__ __forceinline__ ushort f2bf(float f) {
  __hip_bfloat16 h = __float2bfloat16(f);
  return *reinterpret_cast<ushort*>(&h);
}

// async global->LDS, 16 bytes per lane. LDS target must be wave-uniform base
// + lane*16 (our staging layouts satisfy this: lds byte offset == 16*i, i linear in t).
__device__ __forceinline__ void gl2lds16(const ushort* g, ushort* l) {
  __builtin_amdgcn_global_load_lds((const __attribute__((address_space(1))) unsigned int*)g,
                                   (__attribute__((address_space(3))) unsigned int*)l, 16, 0, 0);
}

// ---------------------------------------------------------------------------
// k_prep: x-transpose + cvt(wemb,wq,wk,wv) + tgt LN.
// ---------------------------------------------------------------------------
#define XP_BLKS  4096   // xpose: (b, c-chunk of 32), full s
#define CVP_BLKS 256    // cvt: wemb+wq+wk+wv, grid-stride, 8-float units
#define TG_BLKS  128    // tgt LN rows (padded)

struct PrepArgs {
  const float* x;   ushort* aemb;
  const float* csrc[4]; ushort* cdst[4]; int cn4[4]; int ctotal;  // 8-float units
  const float* qe; const float* g1; const float* be1;
  float* tgt; ushort* tgtB;
};

__global__ __launch_bounds__(256) void k_prep(PrepArgs pa) {
  __shared__ __align__(16) char smem[196 * 40 * 2];   // 15,680 B
  int jid = blockIdx.x;
  const int t = threadIdx.x;

  if (jid < XP_BLKS) {
    // x [B][C][S] f32 -> aemb [(b,s)][C] bf16. Per block: one b, 32 c, all s.
    ushort* xs = (ushort*)smem;
    const int b = jid >> 6, cbase = (jid & 63) * 32;
    const float* xb = pa.x + ((size_t)b * CIN_ + cbase) * S_;
    #pragma unroll
    for (int it = 0; it < 2; ++it) {
      const int u = it * 256 + t;
      if (u < 392) {                       // 49 s-quads x 8 c-quads
        const int j = u >> 3, cq = u & 7;
        const int s = 4 * j;
        float4 a[4];
        #pragma unroll
        for (int r = 0; r < 4; ++r)
          a[r] = *(const float4*)(xb + (size_t)(cq * 4 + r) * S_ + s);
        #pragma unroll
        for (int r = 0; r < 4; ++r) {
          ushort4 o;
          o.x = f2bf(((const float*)&a[0])[r]);
          o.y = f2bf(((const float*)&a[1])[r]);
          o.z = f2bf(((const float*)&a[2])[r]);
          o.w = f2bf(((const float*)&a[3])[r]);
          *(ushort4*)&xs[(s + r) * 40 + cq * 4] = o;
        }
      }
    }
    __syncthreads();
    const int sl = t >> 2, oct = t & 3;    // 4 lanes -> 64 B contiguous store
    #pragma unroll
    for (int sr = 0; sr < 4; ++sr) {
      const int s = sr * 64 + sl;
      if (s < S_) {
        us8 v = *(const us8*)&xs[s * 40 + oct * 8];
        *(us8*)&pa.aemb[((size_t)(b * S_ + s)) * CIN_ + cbase + oct * 8] = v;
      }
    }
    return;
  }
  jid -= XP_BLKS;

  if (jid < CVP_BLKS) {
    int i = jid * 256 + t;
    const int stride = CVP_BLKS * 256;
    for (; i < pa.ctotal; i += stride) {
      int seg = 0, off = i;
      while (off >= pa.cn4[seg]) { off -= pa.cn4[seg]; ++seg; }
      const float4* sp = (const float4*)pa.csrc[seg];
      float4 v0 = sp[2 * off], v1 = sp[2 * off + 1];
      us8 o;
      o[0] = f2bf(v0.x); o[1] = f2bf(v0.y); o[2] = f2bf(v0.z); o[3] = f2bf(v0.w);
      o[4] = f2bf(v1.x); o[5] = f2bf(v1.y); o[6] = f2bf(v1.z); o[7] = f2bf(v1.w);
      ((us8*)pa.cdst[seg])[off] = o;
    }
    return;
  }
  jid -= CVP_BLKS;

  // tgt = LN(2*query_embed)*g1 + be1 -> fp32 [100,768] + bf16 [128,768] (pad 0)
  float* r1 = (float*)smem;
  float* r2 = r1 + 256;
  const int g = jid;
  if (g >= G_) {
    for (int d = t; d < D_; d += 256) pa.tgtB[(size_t)g * D_ + d] = 0;
    return;
  }
  float y[3]; float s = 0.f, sq = 0.f;
  const float* row = pa.qe + (size_t)g * D_;
  #pragma unroll
  for (int i = 0; i < 3; ++i) { float v = 2.f * row[t + i * 256]; y[i] = v; s += v; sq += v * v; }
  r1[t] = s; r2[t] = sq; __syncthreads();
  for (int o = 128; o > 0; o >>= 1) { if (t < o) { r1[t] += r1[t + o]; r2[t] += r2[t + o]; } __syncthreads(); }
  const float mean = r1[0] * (1.f / D_);
  const float var  = r2[0] * (1.f / D_) - mean * mean;
  const float w = rsqrtf(var + 1e-5f);
  #pragma unroll
  for (int i = 0; i < 3; ++i) {
    int d = t + i * 256;
    float v = (y[i] - mean) * w * pa.g1[d] + pa.be1[d];
    pa.tgt[(size_t)g * D_ + d] = v;
    pa.tgtB[(size_t)g * D_ + d] = f2bf(v);
  }
}

// ---------------- bf16 MFMA GEMM core: C[M,N] = A[M,K]*B[N,K]^T + bias -----
// 128x128 tile, BK=32, counted-vmcnt two-barrier k-loop (R11).
// KV mode (Vt != null): cols >= 768 are the V projection, written TRANSPOSED
// into VbT [bh][hd][s].
__device__ __forceinline__ void gemm_core(const ushort* __restrict__ A, const ushort* __restrict__ B,
    const float* __restrict__ bias, const float* __restrict__ bias2,
    float* __restrict__ Cf, ushort* __restrict__ Cb, ushort* __restrict__ Vt,
    int N, int K, int m0, int n0, int relu, ushort* As, ushort* Bs) {
  const int t = threadIdx.x;
  const int lane = t & 63, wave = t >> 6;
  const int quad = lane >> 4, lrow = lane & 15;
  const int wr = (wave >> 1) * 64, wc = (wave & 1) * 64;
  const int srow = t >> 2, scol = (t & 3) * 8;
  const ushort* ag = A + (size_t)(m0 + srow) * K + scol;
  const ushort* bg = B + (size_t)(n0 + srow) * K + scol;
  ushort* asw = As + t * 8;   // linear dest: byte 16*t within buffer
  ushort* bsw = Bs + t * 8;
  f32x4 acc[4][4] = {};
  gl2lds16(ag,                  asw);
  gl2lds16(ag + (size_t)64 * K, asw + 64 * 32);
  gl2lds16(bg,                  bsw);
  gl2lds16(bg + (size_t)64 * K, bsw + 64 * 32);
  int cur = 0;
  for (int k0 = 0; k0 < K; k0 += 32) {
    if (k0 + 32 < K) {                      // prefetch next k-step into other buf
      const int nb = (cur ^ 1) * (128 * 32);
      gl2lds16(ag + k0 + 32,                  asw + nb);
      gl2lds16(ag + k0 + 32 + (size_t)64 * K, asw + nb + 64 * 32);
      gl2lds16(bg + k0 + 32,                  bsw + nb);
      gl2lds16(bg + k0 + 32 + (size_t)64 * K, bsw + nb + 64 * 32);
      asm volatile("s_waitcnt vmcnt(4)" ::: "memory");   // cur staged; prefetch flying
    } else {
      asm volatile("s_waitcnt vmcnt(0)" ::: "memory");
    }
    __builtin_amdgcn_s_barrier();
    __builtin_amdgcn_sched_barrier(0);
    const ushort* as = As + cur * (128 * 32);
    const ushort* bs = Bs + cur * (128 * 32);
    bf16x8 af[4], bfr[4];
    #pragma unroll
    for (int i = 0; i < 4; ++i) af[i] = *(const bf16x8*)&as[(wr + i * 16 + lrow) * 32 + quad * 8];
    #pragma unroll
    for (int j = 0; j < 4; ++j) bfr[j] = *(const bf16x8*)&bs[(wc + j * 16 + lrow) * 32 + quad * 8];
    __builtin_amdgcn_s_setprio(1);
    #pragma unroll
    for (int i = 0; i < 4; ++i)
      #pragma unroll
      for (int j = 0; j < 4; ++j)
        acc[i][j] = __builtin_amdgcn_mfma_f32_16x16x32_bf16(af[i], bfr[j], acc[i][j], 0, 0, 0);
    __builtin_amdgcn_s_setprio(0);
    __builtin_amdgcn_sched_barrier(0);
    __builtin_amdgcn_s_barrier();           // all done reading cur -> safe to overwrite
    __builtin_amdgcn_sched_barrier(0);
    cur ^= 1;
  }
  #pragma unroll
  for (int i = 0; i < 4; ++i) {
    #pragma unroll
    for (int j = 0; j < 4; ++j) {
      const int gcol = n0 + wc + j * 16 + lrow;
      const float bv = (bias2 && gcol >= D_) ? bias2[gcol - D_] : (bias ? bias[gcol] : 0.f);
      if (Vt && gcol >= D_) {
        const int dv = gcol - D_, hh = dv / HD_, hd = dv % HD_;
        const int row0 = m0 + wr + i * 16 + quad * 4;
        const int bb = row0 / S_, ss = row0 % S_;
        ushort4 o;
        o.x = f2bf(acc[i][j][0] + bv);
        o.y = f2bf(acc[i][j][1] + bv);
        o.z = f2bf(acc[i][j][2] + bv);
        o.w = f2bf(acc[i][j][3] + bv);
        *(ushort4*)&Vt[((size_t)(bb * NH_ + hh) * HD_ + hd) * SP_ + ss] = o;
      } else {
        #pragma unroll
        for (int r = 0; r < 4; ++r) {
          const int grow = m0 + wr + i * 16 + quad * 4 + r;
          float v = acc[i][j][r] + bv;
          if (relu) v = fmaxf(v, 0.f);
          if (Cf) Cf[(size_t)grow * N + gcol] = v;
          else    Cb[(size_t)grow * N + gcol] = f2bf(v);
        }
      }
    }
  }
}

__global__ __launch_bounds__(256) void k_gemm(const ushort* __restrict__ A, const ushort* __restrict__ B,
    const float* __restrict__ bias, const float* __restrict__ bias2,
    float* __restrict__ Cf, ushort* __restrict__ Cb, ushort* __restrict__ Vt,
    int N, int K, int nbx, int nm, int relu) {
  __shared__ ushort As[2 * 128 * 32];
  __shared__ ushort Bs[2 * 128 * 32];
  const int l = blockIdx.x;
  const int mb = (l >> 3) / nbx * 8 + (l & 7);
  const int nb = (l >> 3) % nbx;
  if (mb >= nm) return;
  gemm_core(A, B, bias, bias2, Cf, Cb, Vt, N, K, mb * 128, nb * 128, relu, As, Bs);
}
static inline int swz_grid(int nm, int nbx) { return ((nm + 7) & ~7) * nbx; }

// ---------------- 64x128-tile GEMM core (R9/R11) ---------------------------
__device__ __forceinline__ void gemm_core64(const ushort* __restrict__ A, const ushort* __restrict__ B,
    const float* __restrict__ bias, ushort* __restrict__ Cb,
    int N, int K, int m0, int n0, int relu, ushort* As, ushort* Bs) {
  const int t = threadIdx.x;
  const int lane = t & 63, wave = t >> 6;
  const int quad = lane >> 4, lrow = lane & 15;
  const int wr = (wave >> 1) * 32, wc = (wave & 1) * 64;
  const int srow = t >> 2, scol = (t & 3) * 8;
  const ushort* ag = A + (size_t)(m0 + srow) * K + scol;
  const ushort* bg = B + (size_t)(n0 + srow) * K + scol;
  ushort* asw = As + t * 8;
  ushort* bsw = Bs + t * 8;
  f32x4 acc[2][4] = {};
  gl2lds16(ag,                  asw);
  gl2lds16(bg,                  bsw);
  gl2lds16(bg + (size_t)64 * K, bsw + 64 * 32);
  int cur = 0;
  for (int k0 = 0; k0 < K; k0 += 32) {
    if (k0 + 32 < K) {
      gl2lds16(ag + k0 + 32,                  asw + (cur ^ 1) * (64 * 32));
      gl2lds16(bg + k0 + 32,                  bsw + (cur ^ 1) * (128 * 32));
      gl2lds16(bg + k0 + 32 + (size_t)64 * K, bsw + (cur ^ 1) * (128 * 32) + 64 * 32);
      asm volatile("s_waitcnt vmcnt(3)" ::: "memory");
    } else {
      asm volatile("s_waitcnt vmcnt(0)" ::: "memory");
    }
    __builtin_amdgcn_s_barrier();
    __builtin_amdgcn_sched_barrier(0);
    const ushort* as = As + cur * (64 * 32);
    const ushort* bs = Bs + cur * (128 * 32);
    bf16x8 af[2], bfr[4];
    #pragma unroll
    for (int i = 0; i < 2; ++i) af[i] = *(const bf16x8*)&as[(wr + i * 16 + lrow) * 32 + quad * 8];
    #pragma unroll
    for (int j = 0; j < 4; ++j) bfr[j] = *(const bf16x8*)&bs[(wc + j * 16 + lrow) * 32 + quad * 8];
    __builtin_amdgcn_s_setprio(1);
    #pragma unroll
    for (int i = 0; i < 2; ++i)
      #pragma unroll
      for (int j = 0; j < 4; ++j)
        acc[i][j] = __builtin_amdgcn_mfma_f32_16x16x32_bf16(af[i], bfr[j], acc[i][j], 0, 0, 0);
    __builtin_amdgcn_s_setprio(0);
    __builtin_amdgcn_sched_barrier(0);
    __builtin_amdgcn_s_barrier();
    __builtin_amdgcn_sched_barrier(0);
    cur ^= 1;
  }
  #pragma unroll
  for (int i = 0; i < 2; ++i) {
    #pragma unroll
    for (int j = 0; j < 4; ++j) {
      const int gcol = n0 + wc + j * 16 + lrow;
      const float bv = bias ? bias[gcol] : 0.f;
      #pragma unroll
      for (int r = 0; r < 4; ++r) {
        const int grow = m0 + wr + i * 16 + quad * 4 + r;
        float v = acc[i][j][r] + bv;
        if (relu) v = fmaxf(v, 0.f);
        Cb[(size_t)grow * N + gcol] = f2bf(v);
      }
    }
  }
}

__global__ __launch_bounds__(256) void k_gemm64(const ushort* __restrict__ A, const ushort* __restrict__ B,
    const float* __restrict__ bias, ushort* __restrict__ Cb,
    int N, int K, int nbx, int nm, int relu) {
  __shared__ ushort As[2 * 64 * 32];
  __shared__ ushort Bs[2 * 128 * 32];
  const int l = blockIdx.x;
  const int mb = (l >> 3) / nbx * 8 + (l & 7);
  const int nb = (l >> 3) % nbx;
  if (mb >= nm) return;
  gemm_core64(A, B, bias, Cb, N, K, mb * 64, nb * 128, relu, As, Bs);
}

// ---------------- embed dispatch (R15 form): GEMM -> qproj -> cvt ----------
#define EG_BLKS  1200      // swz_grid(196, 6)
#define QP_BLKS  12
#define CV2_BLKS 256

struct EmbArgs {
  const ushort* aemb; const ushort* wembB; const float* b_embed; ushort* memB;
  const ushort* tgtB; const ushort* wqB;   const float* bq;      ushort* qB;
  const float* csrc[3]; ushort* cdst[3]; int cn4[3]; int ctotal;  // 8-float units
};

__global__ __launch_bounds__(256) void k_embed(EmbArgs ea) {
  __shared__ ushort As[2 * 64 * 32];
  __shared__ ushort Bs[2 * 128 * 32];
  int l = blockIdx.x;
  const int t = threadIdx.x;

  if (l < EG_BLKS) {
    const int mb = (l >> 3) / 6 * 8 + (l & 7);
    const int nb = (l >> 3) % 6;
    if (mb >= 196) return;
    gemm_core64(ea.aemb, ea.wembB, ea.b_embed, ea.memB, D_, CIN_, mb * 64, nb * 128, 1, As, Bs);
    return;
  }
  l -= EG_BLKS;

  if (l < QP_BLKS) {
    gemm_core64(ea.tgtB, ea.wqB, ea.bq, ea.qB, D_, D_, (l / 6) * 64, (l % 6) * 128, 0, As, Bs);
    return;
  }
  l -= QP_BLKS;

  int i = l * 256 + t;
  const int stride = CV2_BLKS * 256;
  for (; i < ea.ctotal; i += stride) {
    int seg = 0, off = i;
    while (off >= ea.cn4[seg]) { off -= ea.cn4[seg]; ++seg; }
    const float4* sp = (const float4*)ea.csrc[seg];
    float4 v0 = sp[2 * off], v1 = sp[2 * off + 1];
    us8 o;
    o[0] = f2bf(v0.x); o[1] = f2bf(v0.y); o[2] = f2bf(v0.z); o[3] = f2bf(v0.w);
    o[4] = f2bf(v1.x); o[5] = f2bf(v1.y); o[6] = f2bf(v1.z); o[7] = f2bf(v1.w);
    ((us8*)ea.cdst[seg])[off] = o;
  }
}

// ---------------- fused attention: QK^T + softmax + PV ---------------------
__global__ __launch_bounds__(256) void k_attn(const ushort* __restrict__ qB,
    const ushort* __restrict__ Kb, const ushort* __restrict__ VbT, ushort* __restrict__ ctx) {
  __shared__ ushort lds[GP_ * SP_];   // 50176 B; first 39936 B doubles as K stage
  ushort* Ks = lds;
  ushort* Ps = lds;
  const int h = blockIdx.x, b = blockIdx.y, t = threadIdx.x;
  const int bh = b * NH_ + h;
  const int lane = t & 63, wave = t >> 6;
  const int quad = lane >> 4, c = lane & 15;
  for (int i = t; i < 208 * 12; i += 256) {
    int r = i / 12, col = (i % 12) * 8;
    gl2lds16(Kb + ((size_t)(b * S_ + r)) * D_ + h * HD_ + col, &Ks[i * 8]);
  }
  __syncthreads();
  const float scale = 0.1020620726f;  // 1/sqrt(96)
  f32x4 p[2][13];
  #pragma unroll
  for (int rep = 0; rep < 2; ++rep) {
    const int ii = wave + rep * 4;
    if (ii >= 7) continue;
    bf16x8 af[3];
    #pragma unroll
    for (int ks = 0; ks < 3; ++ks)
      af[ks] = *(const bf16x8*)(qB + ((size_t)(ii * 16 + c)) * D_ + h * HD_ + ks * 32 + quad * 8);
    __builtin_amdgcn_s_setprio(1);
    #pragma unroll
    for (int j = 0; j < 13; ++j) {
      f32x4 a = {};
      #pragma unroll
      for (int ks = 0; ks < 3; ++ks) {
        bf16x8 bf = *(const bf16x8*)&Ks[(j * 16 + c) * HD_ + ks * 32 + quad * 8];
        a = __builtin_amdgcn_mfma_f32_16x16x32_bf16(af[ks], bf, a, 0, 0, 0);
      }
      p[rep][j] = a;
    }
    __builtin_amdgcn_s_setprio(0);
    float m[4] = {-1e30f, -1e30f, -1e30f, -1e30f};
    #pragma unroll
    for (int j = 0; j < 13; ++j)
      #pragma unroll
      for (int r = 0; r < 4; ++r) {
        float v = p[rep][j][r] * scale;
        if (j == 12 && c >= 4) v = -1e30f;   // mask padded s 196..207 (kills NaN too)
        p[rep][j][r] = v;
        m[r] = fmaxf(m[r], v);
      }
    #pragma unroll
    for (int r = 0; r < 4; ++r) {
      m[r] = fmaxf(m[r], __shfl_xor(m[r], 1));
      m[r] = fmaxf(m[r], __shfl_xor(m[r], 2));
      m[r] = fmaxf(m[r], __shfl_xor(m[r], 4));
      m[r] = fmaxf(m[r], __shfl_xor(m[r], 8));
    }
    float lsum[4] = {0.f, 0.f, 0.f, 0.f};
    #pragma unroll
    for (int j = 0; j < 13; ++j)
      #pragma unroll
      for (int r = 0; r < 4; ++r) {
        float e = __expf(p[rep][j][r] - m[r]);
        p[rep][j][r] = e; lsum[r] += e;
      }
    #pragma unroll
    for (int r = 0; r < 4; ++r) {
      lsum[r] += __shfl_xor(lsum[r], 1);
      lsum[r] += __shfl_xor(lsum[r], 2);
      lsum[r] += __shfl_xor(lsum[r], 4);
      lsum[r] += __shfl_xor(lsum[r], 8);
      lsum[r] = 1.f / lsum[r];
    }
    #pragma unroll
    for (int j = 0; j < 13; ++j)
      #pragma unroll
      for (int r = 0; r < 4; ++r)
        p[rep][j][r] *= lsum[r];
  }
  __syncthreads();   // everyone done reading Ks -> safe to overwrite with Ps
  #pragma unroll
  for (int rep = 0; rep < 2; ++rep) {
    const int ii = wave + rep * 4;
    if (ii >= 7) continue;
    #pragma unroll
    for (int r = 0; r < 4; ++r) {
      const int g = ii * 16 + quad * 4 + r;
      #pragma unroll
      for (int j = 0; j < 13; ++j)
        Ps[g * SP_ + j * 16 + c] = f2bf(p[rep][j][r]);
      Ps[g * SP_ + 208 + c] = 0;   // pad s 208..223
    }
  }
  __syncthreads();
  #pragma unroll
  for (int rep = 0; rep < 2; ++rep) {
    const int ii = wave + rep * 4;
    if (ii >= 7) continue;
    bf16x8 af[7];
    #pragma unroll
    for (int k = 0; k < 7; ++k)
      af[k] = *(const bf16x8*)&Ps[(ii * 16 + c) * SP_ + k * 32 + quad * 8];
    #pragma unroll
    for (int j = 0; j < 6; ++j) {
      f32x4 acc = {};
      __builtin_amdgcn_s_setprio(1);
      #pragma unroll
      for (int k = 0; k < 7; ++k) {
        bf16x8 bf = *(const bf16x8*)(VbT + ((size_t)bh * HD_ + j * 16 + c) * SP_ + k * 32 + quad * 8);
        acc = __builtin_amdgcn_mfma_f32_16x16x32_bf16(af[k], bf, acc, 0, 0, 0);
      }
      __builtin_amdgcn_s_setprio(0);
      #pragma unroll
      for (int r = 0; r < 4; ++r) {
        const int g = ii * 16 + quad * 4 + r;
        if (g < G_)
          ctx[((size_t)(b * G_ + g)) * D_ + h * HD_ + j * 16 + c] = f2bf(acc[r]);
      }
    }
  }
}

// ---------------- residual + LayerNorm (add-input bf16) --------------------
// transb: bf16 out written transposed as [g][b][768] (for the head's A-operand)
__global__ __launch_bounds__(256) void k_lnres(const float* __restrict__ resid, int resid_mod,
    const ushort* __restrict__ addB, const float* __restrict__ gamma, const float* __restrict__ beta,
    float* __restrict__ outf, ushort* __restrict__ outb, int transb) {
  const int row = blockIdx.x, t = threadIdx.x;
  __shared__ float r1[256], r2[256];
  const float* rrow = resid + (size_t)(resid_mod ? (row % G_) : row) * D_;
  const ushort* arow = addB + (size_t)row * D_;
  float y[3]; float s = 0.f, sq = 0.f;
  #pragma unroll
  for (int i = 0; i < 3; ++i) {
    int d = t + i * 256;
    float v = rrow[d] + bf2f(arow[d]);
    y[i] = v; s += v; sq += v * v;
  }
  r1[t] = s; r2[t] = sq; __syncthreads();
  for (int o = 128; o > 0; o >>= 1) { if (t < o) { r1[t] += r1[t + o]; r2[t] += r2[t + o]; } __syncthreads(); }
  const float mean = r1[0] * (1.f / D_);
  const float var  = r2[0] * (1.f / D_) - mean * mean;
  const float w = rsqrtf(var + 1e-5f);
  const size_t orow = transb ? ((size_t)(row % G_) * B_ + row / G_) : (size_t)row;
  #pragma unroll
  for (int i = 0; i < 3; ++i) {
    int d = t + i * 256;
    float v = (y[i] - mean) * w * gamma[d] + beta[d];
    if (outf) outf[(size_t)row * D_ + d] = v;
    if (outb) outb[orow * D_ + d] = f2bf(v);
  }
}

// ---------------- grouped head via MFMA (R18: transpose-on-stage) ----------
// grid (G, 7), block 256. B-operand dup_pool[g][d][f-tile] staged straight
// into an XOR-swizzled LDS tile [16 f][768 d] bf16 (byte ^= (f&7)<<4):
// b128 reads are 2-way per 16-lane phase (free); staging writes ~4-way on a
// short phase. Deletes the separate dupT pass (+400 blocks, 34 MB traffic).
__global__ __launch_bounds__(256) void k_head4(const ushort* __restrict__ hT,
    const float* __restrict__ dup, const float* __restrict__ dup_bias, float* __restrict__ out) {
  __shared__ __align__(16) ushort ldsB[16 * 768];   // 24,576 B
  const int g = blockIdx.x, j = blockIdx.y, t = threadIdx.x;
  const int lane = t & 63, wave = t >> 6;
  const int quad = lane >> 4, c = lane & 15;
  const int f0 = j * 16;
  {
    const int dl = t >> 2, fq = t & 3;
    const float* gp = dup + (size_t)g * D_ * DF_;
    #pragma unroll
    for (int p = 0; p < 12; ++p) {
      const int d = p * 64 + dl;
      const int fb = f0 + 4 * fq;
      float v[4];
      if (fb + 4 <= DF_) {
        const float* rp = gp + (size_t)d * DF_ + fb;
        v[0] = rp[0]; v[1] = rp[1]; v[2] = rp[2]; v[3] = rp[3];
      } else {
        #pragma unroll
        for (int r = 0; r < 4; ++r)
          v[r] = (fb + r < DF_) ? gp[(size_t)d * DF_ + fb + r] : 0.f;
      }
      #pragma unroll
      for (int r = 0; r < 4; ++r) {
        const int f = 4 * fq + r;                       // local f 0..15
        const int byte = (f * 768 + d) * 2;
        *(ushort*)((char*)ldsB + (byte ^ ((f & 7) << 4))) = f2bf(v[r]);
      }
    }
  }
  __syncthreads();
  const ushort* ap = hT + ((size_t)g * B_ + wave * 16 + c) * D_;
  f32x4 acc = {};
  #pragma unroll 8
  for (int k0 = 0; k0 < D_; k0 += 32) {
    bf16x8 af = *(const bf16x8*)(ap + k0 + quad * 8);
    const int bbyte = (c * 768 + k0 + quad * 8) * 2;
    bf16x8 bf = *(const bf16x8*)((const char*)ldsB + (bbyte ^ ((c & 7) << 4)));
    acc = __builtin_amdgcn_mfma_f32_16x16x32_bf16(af, bf, acc, 0, 0, 0);
  }
  const int f = j * 16 + c;
  if (f >= DF_) return;
  const int n = g * DF_ + f;
  if (n >= NC_) return;
  const float bv = dup_bias[n];
  #pragma unroll
  for (int r = 0; r < 4; ++r) {
    const int b = wave * 16 + quad * 4 + r;
    out[(size_t)b * NC_ + n] = acc[r] + bv;
  }
}

// ---------------------------------------------------------------------------
// workspace layout (bytes)
// region 0 timeline: aemb (until embed GEMM) -> VbT (KV epilogue .. attn) ->
//                    ffB/ffoB (FFN)
// ---------------------------------------------------------------------------
static constexpr size_t OFF_AEMB  = 0;          // bf16 [12544,2048] = 51,380,224
static constexpr size_t OFF_VBT   = 0;          // bf16 [512,96,224]  = 22,020,096
static constexpr size_t OFF_FF    = 0;          // bf16 [6400,2048] = 26,214,400
static constexpr size_t OFF_FFO   = 26214400;   // bf16 [6400,768]  = 9,830,400 (end 36,044,800)
static constexpr size_t OFF_WEMB  = 51380224;   // bf16 3,145,728
static constexpr size_t OFF_MEM   = 54525952;   // bf16 [12544,768] = 19,267,584
static constexpr size_t OFF_WK    = 73793536;   // 1,179,648   (wk|wv contiguous = fused 1536x768)
static constexpr size_t OFF_WV    = 74973184;   // 1,179,648
static constexpr size_t OFF_WO    = 76152832;   // 1,179,648
static constexpr size_t OFF_W1    = 77332480;   // 3,145,728
static constexpr size_t OFF_W2    = 80478208;   // 3,145,728
static constexpr size_t OFF_KB    = 100827136;  // bf16 [12544,768] = 19,267,584
static constexpr size_t OFF_TGT   = 139362304;  // f32 [100,768] = 307,200
static constexpr size_t OFF_TGTB  = 139669504;  // bf16 [128,768] = 196,608
static constexpr size_t OFF_Q     = 139866112;  // bf16 [128,768] = 196,608
static constexpr size_t OFF_CTX   = 140068864;  // bf16 9,830,400 (also wqB early: dead before attn)
static constexpr size_t OFF_WQ    = OFF_CTX;    // bf16 [768,768] = 1,179,648 (consumed before ctx written)
static constexpr size_t OFF_CTXO  = 149899264;  // bf16 [6400,768] = 9,830,400
static constexpr size_t OFF_TGT2F = 169560064;  // f32 19,660,800
static constexpr size_t OFF_TGT2B = 189220864;  // bf16 9,830,400
static constexpr size_t OFF_HB    = 199051264;  // bf16 [100,64,768] = 9,830,400 (end 208,881,664)

extern "C" void kernel_launch(void* const* d_in, const int* in_sizes, int n_in,
                              void* d_out, int out_size, void* d_ws, size_t ws_size,
                              hipStream_t stream) {
  const float* x           = (const float*)d_in[0];
  const float* w_embed     = (const float*)d_in[1];
  const float* b_embed     = (const float*)d_in[2];
  const float* query_embed = (const float*)d_in[3];
  const float* wq          = (const float*)d_in[4];
  const float* bq          = (const float*)d_in[5];
  const float* wk          = (const float*)d_in[6];
  const float* bk          = (const float*)d_in[7];
  const float* wv          = (const float*)d_in[8];
  const float* bv          = (const float*)d_in[9];
  const float* wo          = (const float*)d_in[10];
  const float* bo          = (const float*)d_in[11];
  const float* g1          = (const float*)d_in[12];
  const float* be1         = (const float*)d_in[13];
  const float* g2          = (const float*)d_in[14];
  const float* be2         = (const float*)d_in[15];
  const float* g3          = (const float*)d_in[16];
  const float* be3         = (const float*)d_in[17];
  const float* w1          = (const float*)d_in[18];
  const float* bl1         = (const float*)d_in[19];
  const float* w2          = (const float*)d_in[20];
  const float* bl2         = (const float*)d_in[21];
  const float* dup_pool    = (const float*)d_in[22];
  const float* dup_bias    = (const float*)d_in[23];
  float* out = (float*)d_out;
  char* ws = (char*)d_ws;

  ushort* aemb  = (ushort*)(ws + OFF_AEMB);
  ushort* wembB = (ushort*)(ws + OFF_WEMB);
  ushort* memB  = (ushort*)(ws + OFF_MEM);
  ushort* wkvB  = (ushort*)(ws + OFF_WK);    // fused [1536][768]
  ushort* wkB   = (ushort*)(ws + OFF_WK);
  ushort* wvB   = (ushort*)(ws + OFF_WV);
  ushort* woB   = (ushort*)(ws + OFF_WO);
  ushort* w1B   = (ushort*)(ws + OFF_W1);
  ushort* w2B   = (ushort*)(ws + OFF_W2);
  ushort* wqB   = (ushort*)(ws + OFF_WQ);
  ushort* Kb    = (ushort*)(ws + OFF_KB);
  float*  tgtF  = (float*)(ws + OFF_TGT);
  ushort* tgtB  = (ushort*)(ws + OFF_TGTB);
  ushort* qB    = (ushort*)(ws + OFF_Q);
  ushort* VbT   = (ushort*)(ws + OFF_VBT);
  ushort* ctxB  = (ushort*)(ws + OFF_CTX);
  ushort* ctxoB = (ushort*)(ws + OFF_CTXO);
  float*  tgt2F = (float*)(ws + OFF_TGT2F);
  ushort* tgt2B = (ushort*)(ws + OFF_TGT2B);
  ushort* ffB   = (ushort*)(ws + OFF_FF);
  ushort* ffoB  = (ushort*)(ws + OFF_FFO);
  ushort* hT    = (ushort*)(ws + OFF_HB);

  // 1. prep: x-transpose + cvt(wemb,wq,wk,wv) + tgt LN
  PrepArgs pa;
  pa.x = x; pa.aemb = aemb;
  pa.csrc[0] = w_embed; pa.cdst[0] = wembB; pa.cn4[0] = D_ * CIN_ / 8;
  pa.csrc[1] = wq;      pa.cdst[1] = wqB;   pa.cn4[1] = D_ * D_ / 8;
  pa.csrc[2] = wk;      pa.cdst[2] = wkB;   pa.cn4[2] = D_ * D_ / 8;
  pa.csrc[3] = wv;      pa.cdst[3] = wvB;   pa.cn4[3] = D_ * D_ / 8;
  pa.ctotal = pa.cn4[0] + pa.cn4[1] + pa.cn4[2] + pa.cn4[3];
  pa.qe = query_embed; pa.g1 = g1; pa.be1 = be1; pa.tgt = tgtF; pa.tgtB = tgtB;
  k_prep<<<XP_BLKS + CVP_BLKS + TG_BLKS, 256, 0, stream>>>(pa);

  // 2. embed dispatch: embed GEMM (+relu) -> q-proj -> wo/w1/w2 cvt
  EmbArgs ea;
  ea.aemb = aemb; ea.wembB = wembB; ea.b_embed = b_embed; ea.memB = memB;
  ea.tgtB = tgtB; ea.wqB = wqB; ea.bq = bq; ea.qB = qB;
  ea.csrc[0] = wo; ea.cdst[0] = woB; ea.cn4[0] = D_ * D_ / 8;
  ea.csrc[1] = w1; ea.cdst[1] = w1B; ea.cn4[1] = FF_ * D_ / 8;
  ea.csrc[2] = w2; ea.cdst[2] = w2B; ea.cn4[2] = D_ * FF_ / 8;
  ea.ctotal = ea.cn4[0] + ea.cn4[1] + ea.cn4[2];
  k_embed<<<EG_BLKS + QP_BLKS + CV2_BLKS, 256, 0, stream>>>(ea);

  // 3. fused K|V projection: K -> Kb, V -> VbT (transposed)
  k_gemm<<<swz_grid(98, 12), 256, 0, stream>>>(memB, wkvB, bk, bv, nullptr, Kb, VbT,
                                               D_, D_, 12, 98, 0);

  // 4. fused attention (QK^T + softmax + PV)
  k_attn<<<dim3(NH_, B_), 256, 0, stream>>>(qB, Kb, VbT, ctxB);

  // 5. ctx @ wo^T + bo -> bf16 [6400, 768] (64-row tiles)
  k_gemm64<<<swz_grid(100, 6), 256, 0, stream>>>(ctxB, woB, bo, ctxoB, D_, D_, 6, 100, 0);

  // 6. tgt2 = LN(tgt + ctxo)
  k_lnres<<<BG_, 256, 0, stream>>>(tgtF, 1, ctxoB, g2, be2, tgt2F, tgt2B, 0);

  // 7-8. FFN
  k_gemm<<<swz_grid(50, 16), 256, 0, stream>>>(tgt2B, w1B, bl1, nullptr, nullptr, ffB, nullptr,
                                               FF_, D_, 16, 50, 1);
  k_gemm64<<<swz_grid(100, 6), 256, 0, stream>>>(ffB, w2B, bl2, ffoB, D_, FF_, 6, 100, 0);

  // 9. h = LN(tgt2 + ffo) -> bf16 transposed [g][64][768]
  k_lnres<<<BG_, 256, 0, stream>>>(tgt2F, 0, ffoB, g3, be3, nullptr, hT, 1);

  // 10. grouped head -> logits fp32 [64, 9605] via MFMA (dup staged in-kernel)
  k_head4<<<dim3(G_, 7), 256, 0, stream>>>(hT, dup_pool, dup_bias, out);
}